// Round 1
// baseline (2050.924 us; speedup 1.0000x reference)
//
#include <hip/hip_runtime.h>

#define NN 50000
#define NE 800000
#define NG 128
#define DIN 1280
#define HIDDEN 256
#define BNS 0.9999950000374997f
#define ATT_SCALE 0.027950849718747373f
#define LN_EPS 1e-5f

typedef __attribute__((ext_vector_type(8))) short short8;
typedef __attribute__((ext_vector_type(4))) float floatx4;

__device__ __forceinline__ float b2f(unsigned short u) {
  return __uint_as_float(((unsigned int)u) << 16);
}
__device__ __forceinline__ unsigned short f2b(float f) {
  unsigned int x = __float_as_uint(f);
  x += 0x7fffu + ((x >> 16) & 1u);
  return (unsigned short)(x >> 16);
}

// ---------------- weight prep ----------------
// src [K][Nc] fp32 -> dst [Nc][K] bf16 (transposed, for GEMM B operand)
__global__ void transpose_w_k(const float* __restrict__ src, unsigned short* __restrict__ dst,
                              int K, int Nc) {
  int idx = blockIdx.x * 256 + threadIdx.x;
  if (idx >= K * Nc) return;
  int n = idx / K, k = idx % K;
  dst[idx] = f2b(src[(size_t)k * Nc + n]);
}

// qw/kw/vw [4][256][256] -> dst [3072][256] rows: q heads 0-3, k heads, v heads
__global__ void qkv_transpose_k(const float* __restrict__ qw, const float* __restrict__ kw,
                                const float* __restrict__ vw, unsigned short* __restrict__ dst) {
  int idx = blockIdx.x * 256 + threadIdx.x;
  if (idx >= 3072 * 256) return;
  int r = idx >> 8;
  int d = idx & 255;
  int t = r >> 10;
  int h = (r >> 8) & 3;
  int e2 = r & 255;
  const float* W = (t == 0) ? qw : (t == 1) ? kw : vw;
  dst[idx] = f2b(W[((size_t)h * 256 + d) * 256 + e2]);
}

__global__ void cvt_bf16_k(const float* __restrict__ src, unsigned short* __restrict__ dst, int n4) {
  int i = blockIdx.x * 256 + threadIdx.x;
  if (i >= n4) return;
  float4 v = ((const float4*)src)[i];
  ushort4 o;
  o.x = f2b(v.x); o.y = f2b(v.y); o.z = f2b(v.z); o.w = f2b(v.w);
  ((ushort4*)dst)[i] = o;
}

// ---------------- graph structure ----------------
__global__ void graph_bounds_k(const int* __restrict__ gid, int* __restrict__ start, int n) {
  int i = blockIdx.x * 256 + threadIdx.x;
  if (i >= n) return;
  int g = gid[i];
  if (i == 0) {
    for (int gg = 0; gg <= g; ++gg) start[gg] = 0;
  } else {
    int gp = gid[i - 1];
    for (int gg = gp + 1; gg <= g; ++gg) start[gg] = i;
  }
  if (i == n - 1) {
    for (int gg = g + 1; gg <= NG; ++gg) start[gg] = n;
  }
}

__global__ void degrees_k(const int* __restrict__ src, const int* __restrict__ dst,
                          int* __restrict__ deg_out, int* __restrict__ deg_in, int e) {
  int i = blockIdx.x * 256 + threadIdx.x;
  if (i >= e) return;
  atomicAdd(&deg_out[src[i]], 1);
  atomicAdd(&deg_in[dst[i]], 1);
}

__global__ void invsqrt_k(const int* __restrict__ deg_out, const int* __restrict__ deg_in,
                          float* __restrict__ ns, float* __restrict__ nd, int n) {
  int i = blockIdx.x * 256 + threadIdx.x;
  if (i >= n) return;
  int a = deg_out[i]; if (a < 1) a = 1;
  int b = deg_in[i];  if (b < 1) b = 1;
  ns[i] = rsqrtf((float)a);
  nd[i] = rsqrtf((float)b);
}

__global__ void scan_k(const int* __restrict__ deg, int* __restrict__ row_ptr, int n) {
  __shared__ int buf[1024];
  __shared__ int carry_s;
  int tid = threadIdx.x;
  if (tid == 0) carry_s = 0;
  __syncthreads();
  for (int base = 0; base < n; base += 1024) {
    int i = base + tid;
    int v = (i < n) ? deg[i] : 0;
    buf[tid] = v;
    __syncthreads();
    for (int off = 1; off < 1024; off <<= 1) {
      int t = (tid >= off) ? buf[tid - off] : 0;
      __syncthreads();
      buf[tid] += t;
      __syncthreads();
    }
    int carry = carry_s;
    if (i < n) row_ptr[i] = carry + buf[tid] - v;
    __syncthreads();
    if (tid == 1023) carry_s = carry + buf[1023];
    __syncthreads();
  }
  if (tid == 0) row_ptr[n] = carry_s;
}

__global__ void fill_csr_k(const int* __restrict__ src, const int* __restrict__ dst,
                           const int* __restrict__ row_ptr, int* __restrict__ fill,
                           int* __restrict__ csr_src, int e) {
  int i = blockIdx.x * 256 + threadIdx.x;
  if (i >= e) return;
  int d = dst[i];
  int pos = row_ptr[d] + atomicAdd(&fill[d], 1);
  csr_src[pos] = src[i];
}

// ---------------- init_avg_h (output 1) ----------------
__global__ void init_avg_k(const float* __restrict__ h, const int* __restrict__ start,
                           float* __restrict__ out1) {
  int g = blockIdx.x;
  int c = blockIdx.y * 256 + threadIdx.x;
  int s = start[g], e = start[g + 1];
  float acc = 0.f;
  for (int i = s; i < e; ++i) acc += h[(size_t)i * DIN + c];
  float cnt = (float)(e - s);
  if (cnt < 1.f) cnt = 1.f;
  out1[(size_t)g * DIN + c] = acc / cnt;
}

// ---------------- bf16 MFMA GEMM ----------------
// C[M,Nc] = A[M,K](bf16,row-major) * Bt[Nc,K](bf16, = W^T)
// MODE 0: bf16 out; 1: fp32 out; 2: +bias, relu, bf16 out
template <int MODE>
__global__ __launch_bounds__(256, 2) void gemm_bf16(const unsigned short* __restrict__ A,
                                                    const unsigned short* __restrict__ Bt,
                                                    void* __restrict__ Cout,
                                                    const float* __restrict__ bias,
                                                    int M, int K, int Nc) {
  __shared__ unsigned short lA[8192];  // [kb 0..7][128 rows][8], chunk index swizzled by ^kb
  __shared__ unsigned short lB[8192];
  const int tid = threadIdx.x;
  const int m0 = blockIdx.x * 128;
  const int n0 = blockIdx.y * 128;
  const int w = tid >> 6;
  const int lane = tid & 63;
  const int wr = (w >> 1) * 64;
  const int wc = (w & 1) * 64;
  const int quad = lane >> 4;
  const int l15 = lane & 15;
  const int js = tid & 7;
  const int mbase = tid >> 3;

  floatx4 acc[4][4];
#pragma unroll
  for (int i = 0; i < 4; ++i)
#pragma unroll
    for (int j = 0; j < 4; ++j) acc[i][j] = (floatx4)0.0f;

  for (int k0 = 0; k0 < K; k0 += 64) {
    __syncthreads();
#pragma unroll
    for (int it = 0; it < 4; ++it) {
      int m = it * 32 + mbase;
      int gm = m0 + m;
      if (gm >= M) gm = M - 1;
      uint4 va = *(const uint4*)(A + (size_t)gm * K + k0 + js * 8);
      int ci_ = js * 128 + (m ^ js);
      *(uint4*)(lA + ci_ * 8) = va;
      int gn = n0 + m;
      uint4 vb = *(const uint4*)(Bt + (size_t)gn * K + k0 + js * 8);
      *(uint4*)(lB + ci_ * 8) = vb;
    }
    __syncthreads();
#pragma unroll
    for (int ks = 0; ks < 2; ++ks) {
      int kb = ks * 4 + quad;
      short8 af[4], bfr[4];
#pragma unroll
      for (int ri = 0; ri < 4; ++ri) {
        int r = wr + ri * 16 + l15;
        af[ri] = *(const short8*)(lA + (kb * 128 + (r ^ kb)) * 8);
      }
#pragma unroll
      for (int ci = 0; ci < 4; ++ci) {
        int c = wc + ci * 16 + l15;
        bfr[ci] = *(const short8*)(lB + (kb * 128 + (c ^ kb)) * 8);
      }
#pragma unroll
      for (int ri = 0; ri < 4; ++ri)
#pragma unroll
        for (int ci = 0; ci < 4; ++ci)
          acc[ri][ci] = __builtin_amdgcn_mfma_f32_16x16x32_bf16(af[ri], bfr[ci], acc[ri][ci], 0, 0, 0);
    }
  }
#pragma unroll
  for (int ri = 0; ri < 4; ++ri) {
    int row = m0 + wr + ri * 16 + quad * 4;
#pragma unroll
    for (int ci = 0; ci < 4; ++ci) {
      int col = n0 + wc + ci * 16 + l15;
      float bv = (MODE == 2) ? bias[col] : 0.f;
#pragma unroll
      for (int r = 0; r < 4; ++r) {
        if (row + r < M) {
          float v = acc[ri][ci][r];
          if (MODE == 2) { v += bv; v = fmaxf(v, 0.f); }
          if (MODE == 1)
            ((float*)Cout)[(size_t)(row + r) * Nc + col] = v;
          else
            ((unsigned short*)Cout)[(size_t)(row + r) * Nc + col] = f2b(v);
        }
      }
    }
  }
}

// ---------------- GCN aggregation: out = act(bn(sum_e ns[u]*m[u] * nd + bias)) [+resid] ----------------
__global__ void gcn_agg_k(const unsigned short* __restrict__ m, int ldm,
                          const int* __restrict__ row_ptr, const int* __restrict__ csr_src,
                          const float* __restrict__ ns, const float* __restrict__ nd,
                          const float* __restrict__ bias,
                          const float* __restrict__ bng, const float* __restrict__ bnb,
                          const unsigned short* __restrict__ resid, int ldr,
                          unsigned short* __restrict__ out, int ldo) {
  int node = blockIdx.x * 4 + (threadIdx.x >> 6);
  if (node >= NN) return;
  int lane = threadIdx.x & 63;
  int s = row_ptr[node], e = row_ptr[node + 1];
  float a0 = 0, a1 = 0, a2 = 0, a3 = 0;
  for (int i = s; i < e; ++i) {
    int u = csr_src[i];
    float w = ns[u];
    ushort4 v = *(const ushort4*)(m + (size_t)u * ldm + lane * 4);
    a0 += w * b2f(v.x); a1 += w * b2f(v.y); a2 += w * b2f(v.z); a3 += w * b2f(v.w);
  }
  float ndv = nd[node];
  int col = lane * 4;
  float vals[4] = {a0, a1, a2, a3};
  ushort4 o;
#pragma unroll
  for (int c = 0; c < 4; ++c) {
    float v = vals[c] * ndv + bias[col + c];
    v = bng[col + c] * v * BNS + bnb[col + c];
    v = fmaxf(v, 0.f);
    if (resid) v += b2f(resid[(size_t)node * ldr + col + c]);
    ((unsigned short*)&o)[c] = f2b(v);
  }
  *(ushort4*)(out + (size_t)node * ldo + col) = o;
}

// ---------------- GAT el/er ----------------
__global__ void elr_k(const unsigned short* __restrict__ f, int ldf,
                      const float* __restrict__ al, const float* __restrict__ ar,
                      float* __restrict__ elr) {
  int node = blockIdx.x * 4 + (threadIdx.x >> 6);
  if (node >= NN) return;
  int lane = threadIdx.x & 63;
  int head = lane >> 4;
  int col = lane * 4;
  int dcol = col & 63;
  ushort4 v = *(const ushort4*)(f + (size_t)node * ldf + col);
  float pl = 0, pr = 0;
#pragma unroll
  for (int c = 0; c < 4; ++c) {
    float x = b2f(((unsigned short*)&v)[c]);
    pl += x * al[head * 64 + dcol + c];
    pr += x * ar[head * 64 + dcol + c];
  }
#pragma unroll
  for (int off = 1; off < 16; off <<= 1) {
    pl += __shfl_xor(pl, off);
    pr += __shfl_xor(pr, off);
  }
  if ((lane & 15) == 0) {
    elr[(size_t)node * 8 + head] = pl;
    elr[(size_t)node * 8 + 4 + head] = pr;
  }
}

// ---------------- GAT aggregation (edge softmax + weighted sum + bn + elu [+resid]) ----------------
__global__ void gat_agg_k(const unsigned short* __restrict__ f, int ldf,
                          const int* __restrict__ row_ptr, const int* __restrict__ csr_src,
                          const float* __restrict__ elr,
                          const float* __restrict__ bias,
                          const float* __restrict__ bng, const float* __restrict__ bnb,
                          const unsigned short* __restrict__ resid, int ldr,
                          unsigned short* __restrict__ out, int ldo) {
  int node = blockIdx.x * 4 + (threadIdx.x >> 6);
  if (node >= NN) return;
  int lane = threadIdx.x & 63;
  int s = row_ptr[node], e = row_ptr[node + 1];
  float4 er = *(const float4*)(elr + (size_t)node * 8 + 4);
  float m0 = -1e30f, m1 = -1e30f, m2 = -1e30f, m3 = -1e30f;
  for (int i = s + lane; i < e; i += 64) {
    int u = csr_src[i];
    float4 el = *(const float4*)(elr + (size_t)u * 8);
    float t;
    t = el.x + er.x; t = t > 0.f ? t : 0.2f * t; m0 = fmaxf(m0, t);
    t = el.y + er.y; t = t > 0.f ? t : 0.2f * t; m1 = fmaxf(m1, t);
    t = el.z + er.z; t = t > 0.f ? t : 0.2f * t; m2 = fmaxf(m2, t);
    t = el.w + er.w; t = t > 0.f ? t : 0.2f * t; m3 = fmaxf(m3, t);
  }
#pragma unroll
  for (int off = 1; off < 64; off <<= 1) {
    m0 = fmaxf(m0, __shfl_xor(m0, off));
    m1 = fmaxf(m1, __shfl_xor(m1, off));
    m2 = fmaxf(m2, __shfl_xor(m2, off));
    m3 = fmaxf(m3, __shfl_xor(m3, off));
  }
  float s0 = 0, s1 = 0, s2 = 0, s3 = 0;
  for (int i = s + lane; i < e; i += 64) {
    int u = csr_src[i];
    float4 el = *(const float4*)(elr + (size_t)u * 8);
    float t;
    t = el.x + er.x; t = t > 0.f ? t : 0.2f * t; s0 += expf(t - m0);
    t = el.y + er.y; t = t > 0.f ? t : 0.2f * t; s1 += expf(t - m1);
    t = el.z + er.z; t = t > 0.f ? t : 0.2f * t; s2 += expf(t - m2);
    t = el.w + er.w; t = t > 0.f ? t : 0.2f * t; s3 += expf(t - m3);
  }
#pragma unroll
  for (int off = 1; off < 64; off <<= 1) {
    s0 += __shfl_xor(s0, off);
    s1 += __shfl_xor(s1, off);
    s2 += __shfl_xor(s2, off);
    s3 += __shfl_xor(s3, off);
  }
  int head = lane >> 4;
  float erh = head == 0 ? er.x : head == 1 ? er.y : head == 2 ? er.z : er.w;
  float mh = head == 0 ? m0 : head == 1 ? m1 : head == 2 ? m2 : m3;
  float sh = head == 0 ? s0 : head == 1 ? s1 : head == 2 ? s2 : s3;
  float inv_sh = (sh > 0.f) ? 1.f / sh : 0.f;
  float a0 = 0, a1 = 0, a2 = 0, a3 = 0;
  for (int i = s; i < e; ++i) {
    int u = csr_src[i];
    float t = elr[(size_t)u * 8 + head] + erh;
    t = t > 0.f ? t : 0.2f * t;
    float wgt = expf(t - mh) * inv_sh;
    ushort4 v = *(const ushort4*)(f + (size_t)u * ldf + lane * 4);
    a0 += wgt * b2f(v.x); a1 += wgt * b2f(v.y); a2 += wgt * b2f(v.z); a3 += wgt * b2f(v.w);
  }
  int col = lane * 4;
  float vals[4] = {a0, a1, a2, a3};
  ushort4 o;
#pragma unroll
  for (int c = 0; c < 4; ++c) {
    float v = vals[c] + bias[col + c];
    v = bng[col + c] * v * BNS + bnb[col + c];
    v = (v > 0.f) ? v : (expf(v) - 1.f);
    if (resid) v += b2f(resid[(size_t)node * ldr + col + c]);
    ((unsigned short*)&o)[c] = f2b(v);
  }
  *(ushort4*)(out + (size_t)node * ldo + col) = o;
}

// ---------------- gate combine ----------------
__global__ void combine_k(const float* __restrict__ glogit, const float* __restrict__ gate_b,
                          const unsigned short* __restrict__ xcat,
                          float* __restrict__ xf, unsigned short* __restrict__ xb) {
  int idx = blockIdx.x * 256 + threadIdx.x;
  if (idx >= NN * 64) return;
  int node = idx >> 6;
  int c = (idx & 63) * 4;
  float4 gl = *(const float4*)(glogit + (size_t)node * HIDDEN + c);
  ushort4 hgv = *(const ushort4*)(xcat + (size_t)node * 512 + c);
  ushort4 hav = *(const ushort4*)(xcat + (size_t)node * 512 + 256 + c);
  float4 o;
  float g;
  g = 1.f / (1.f + expf(-(gl.x + gate_b[c + 0]))); o.x = g * b2f(hgv.x) + (1.f - g) * b2f(hav.x);
  g = 1.f / (1.f + expf(-(gl.y + gate_b[c + 1]))); o.y = g * b2f(hgv.y) + (1.f - g) * b2f(hav.y);
  g = 1.f / (1.f + expf(-(gl.z + gate_b[c + 2]))); o.z = g * b2f(hgv.z) + (1.f - g) * b2f(hav.z);
  g = 1.f / (1.f + expf(-(gl.w + gate_b[c + 3]))); o.w = g * b2f(hgv.w) + (1.f - g) * b2f(hav.w);
  *(float4*)(xf + (size_t)node * HIDDEN + c) = o;
  ushort4 ob;
  ob.x = f2b(o.x); ob.y = f2b(o.y); ob.z = f2b(o.z); ob.w = f2b(o.w);
  *(ushort4*)(xb + (size_t)node * HIDDEN + c) = ob;
}

// ---------------- attention scores ----------------
__global__ void att_k(const unsigned short* __restrict__ qkv, float* __restrict__ att) {
  int node = blockIdx.x * 4 + (threadIdx.x >> 6);
  if (node >= NN) return;
  int lane = threadIdx.x & 63;
  const unsigned short* q = qkv + (size_t)node * 3072;
  const unsigned short* k = q + 1024;
#pragma unroll
  for (int h = 0; h < 4; ++h) {
    ushort4 qv = *(const ushort4*)(q + h * 256 + lane * 4);
    ushort4 kv = *(const ushort4*)(k + h * 256 + lane * 4);
    float p = b2f(qv.x) * b2f(kv.x) + b2f(qv.y) * b2f(kv.y) +
              b2f(qv.z) * b2f(kv.z) + b2f(qv.w) * b2f(kv.w);
#pragma unroll
    for (int off = 1; off < 64; off <<= 1) p += __shfl_xor(p, off);
    if (lane == 0) att[(size_t)node * 4 + h] = p * ATT_SCALE;
  }
}

// ---------------- per-graph node softmax ----------------
__global__ void gsoftmax_k(const float* __restrict__ att, const int* __restrict__ start,
                           float* __restrict__ alpha) {
  int g = blockIdx.x;
  int s = start[g], e = start[g + 1];
  int tid = threadIdx.x;
  __shared__ float red[256];
  __shared__ float mh[4], sh[4];
  float lm[4] = {-1e30f, -1e30f, -1e30f, -1e30f};
  for (int i = s + tid; i < e; i += 256) {
    float4 a = *(const float4*)(att + (size_t)i * 4);
    lm[0] = fmaxf(lm[0], a.x); lm[1] = fmaxf(lm[1], a.y);
    lm[2] = fmaxf(lm[2], a.z); lm[3] = fmaxf(lm[3], a.w);
  }
#pragma unroll
  for (int h = 0; h < 4; ++h) {
    red[tid] = lm[h]; __syncthreads();
    for (int off = 128; off > 0; off >>= 1) {
      if (tid < off) red[tid] = fmaxf(red[tid], red[tid + off]);
      __syncthreads();
    }
    if (tid == 0) mh[h] = red[0];
    __syncthreads();
  }
  float ls[4] = {0, 0, 0, 0};
  for (int i = s + tid; i < e; i += 256) {
    float4 a = *(const float4*)(att + (size_t)i * 4);
    ls[0] += expf(a.x - mh[0]); ls[1] += expf(a.y - mh[1]);
    ls[2] += expf(a.z - mh[2]); ls[3] += expf(a.w - mh[3]);
  }
#pragma unroll
  for (int h = 0; h < 4; ++h) {
    red[tid] = ls[h]; __syncthreads();
    for (int off = 128; off > 0; off >>= 1) {
      if (tid < off) red[tid] += red[tid + off];
      __syncthreads();
    }
    if (tid == 0) sh[h] = red[0];
    __syncthreads();
  }
  for (int i = s + tid; i < e; i += 256) {
    float4 a = *(const float4*)(att + (size_t)i * 4);
    float4 o;
    o.x = expf(a.x - mh[0]) / sh[0];
    o.y = expf(a.y - mh[1]) / sh[1];
    o.z = expf(a.z - mh[2]) / sh[2];
    o.w = expf(a.w - mh[3]) / sh[3];
    *(float4*)(alpha + (size_t)i * 4) = o;
  }
}

// ---------------- scale V by alpha ----------------
__global__ void scalev_k(const unsigned short* __restrict__ qkv, const float* __restrict__ alpha,
                         unsigned short* __restrict__ vs) {
  int idx = blockIdx.x * 256 + threadIdx.x;
  if (idx >= NN * 256) return;
  int node = idx >> 8;
  int c = (idx & 255) * 4;
  int h = c >> 8;
  float a = alpha[(size_t)node * 4 + h];
  ushort4 v = *(const ushort4*)(qkv + (size_t)node * 3072 + 2048 + c);
  ushort4 o;
  o.x = f2b(b2f(v.x) * a); o.y = f2b(b2f(v.y) * a);
  o.z = f2b(b2f(v.z) * a); o.w = f2b(b2f(v.w) * a);
  *(ushort4*)(vs + (size_t)node * 1024 + c) = o;
}

// ---------------- LayerNorms ----------------
__global__ void ln1_k(const float* __restrict__ mo, const float* __restrict__ x,
                      const float* __restrict__ g, const float* __restrict__ b,
                      float* __restrict__ x1f, unsigned short* __restrict__ x1b) {
  int node = blockIdx.x * 4 + (threadIdx.x >> 6);
  if (node >= NN) return;
  int lane = threadIdx.x & 63;
  int c = lane * 4;
  float4 a = *(const float4*)(mo + (size_t)node * HIDDEN + c);
  float4 xx = *(const float4*)(x + (size_t)node * HIDDEN + c);
  float v0 = a.x + xx.x, v1 = a.y + xx.y, v2 = a.z + xx.z, v3 = a.w + xx.w;
  float sm = v0 + v1 + v2 + v3;
#pragma unroll
  for (int off = 1; off < 64; off <<= 1) sm += __shfl_xor(sm, off);
  float mu = sm * (1.f / 256.f);
  float d0 = v0 - mu, d1 = v1 - mu, d2 = v2 - mu, d3 = v3 - mu;
  float sq = d0 * d0 + d1 * d1 + d2 * d2 + d3 * d3;
#pragma unroll
  for (int off = 1; off < 64; off <<= 1) sq += __shfl_xor(sq, off);
  float inv = rsqrtf(sq * (1.f / 256.f) + LN_EPS);
  float4 o;
  o.x = g[c + 0] * d0 * inv + b[c + 0];
  o.y = g[c + 1] * d1 * inv + b[c + 1];
  o.z = g[c + 2] * d2 * inv + b[c + 2];
  o.w = g[c + 3] * d3 * inv + b[c + 3];
  *(float4*)(x1f + (size_t)node * HIDDEN + c) = o;
  ushort4 ob;
  ob.x = f2b(o.x); ob.y = f2b(o.y); ob.z = f2b(o.z); ob.w = f2b(o.w);
  *(ushort4*)(x1b + (size_t)node * HIDDEN + c) = ob;
}

__global__ void ln2_k(const float* __restrict__ ff2o, const float* __restrict__ ffb2,
                      const float* __restrict__ x1f,
                      const float* __restrict__ g, const float* __restrict__ b,
                      float* __restrict__ x2) {
  int node = blockIdx.x * 4 + (threadIdx.x >> 6);
  if (node >= NN) return;
  int lane = threadIdx.x & 63;
  int c = lane * 4;
  float4 a = *(const float4*)(ff2o + (size_t)node * HIDDEN + c);
  float4 xx = *(const float4*)(x1f + (size_t)node * HIDDEN + c);
  float v0 = a.x + ffb2[c + 0] + xx.x, v1 = a.y + ffb2[c + 1] + xx.y;
  float v2 = a.z + ffb2[c + 2] + xx.z, v3 = a.w + ffb2[c + 3] + xx.w;
  float sm = v0 + v1 + v2 + v3;
#pragma unroll
  for (int off = 1; off < 64; off <<= 1) sm += __shfl_xor(sm, off);
  float mu = sm * (1.f / 256.f);
  float d0 = v0 - mu, d1 = v1 - mu, d2 = v2 - mu, d3 = v3 - mu;
  float sq = d0 * d0 + d1 * d1 + d2 * d2 + d3 * d3;
#pragma unroll
  for (int off = 1; off < 64; off <<= 1) sq += __shfl_xor(sq, off);
  float inv = rsqrtf(sq * (1.f / 256.f) + LN_EPS);
  float4 o;
  o.x = g[c + 0] * d0 * inv + b[c + 0];
  o.y = g[c + 1] * d1 * inv + b[c + 1];
  o.z = g[c + 2] * d2 * inv + b[c + 2];
  o.w = g[c + 3] * d3 * inv + b[c + 3];
  *(float4*)(x2 + (size_t)node * HIDDEN + c) = o;
}

// ---------------- readout (output 0) ----------------
__global__ void readout_k(const float* __restrict__ x2, const int* __restrict__ start,
                          float* __restrict__ out0) {
  int g = blockIdx.x;
  int c = threadIdx.x;
  float acc = 0.f;
  for (int i = start[g]; i < start[g + 1]; ++i) acc += x2[(size_t)i * HIDDEN + c];
  out0[(size_t)g * HIDDEN + c] = acc;
}

// ---------------- workspace layout (bytes) ----------------
// bufA is phase-overlapped: phase1 {h_bf,c01,hg0,ha0,m1,f1} / phase2 {qkv} / phase3 {ff1o,ff2o,x2}
static const size_t OFF_BUFA   = 0;
static const size_t OFF_XCAT   = 307200000;
static const size_t OFF_GLOGIT = OFF_XCAT + 51200000;   // also mo
static const size_t OFF_XF     = OFF_GLOGIT + 51200000;
static const size_t OFF_XB     = OFF_XF + 51200000;
static const size_t OFF_VS     = OFF_XB + 25600000;     // also x1f (+0) and x1b (+51200000)
static const size_t OFF_ATT    = OFF_VS + 102400000;
static const size_t OFF_ALPHA  = OFF_ATT + 800000;
static const size_t OFF_ELR0   = OFF_ALPHA + 800000;
static const size_t OFF_ELR1   = OFF_ELR0 + 1600000;
static const size_t OFF_START  = OFF_ELR1 + 1600000;
static const size_t OFF_DEGO   = OFF_START + 1024;
static const size_t OFF_DEGI   = OFF_DEGO + 200704;
static const size_t OFF_NS     = OFF_DEGI + 200704;
static const size_t OFF_ND     = OFF_NS + 200704;
static const size_t OFF_ROWP   = OFF_ND + 200704;
static const size_t OFF_FILL   = OFF_ROWP + 200704;
static const size_t OFF_CSRS   = OFF_FILL + 200704;
static const size_t OFF_W01T   = OFF_CSRS + 3200000;
static const size_t OFF_W1T    = OFF_W01T + 1310720;
static const size_t OFF_W1GT   = OFF_W1T + 131072;
static const size_t OFF_GATEWT = OFF_W1GT + 131072;
static const size_t OFF_WQKVT  = OFF_GATEWT + 262144;
static const size_t OFF_CTWT   = OFF_WQKVT + 1572864;
static const size_t OFF_FFW1T  = OFF_CTWT + 524288;
static const size_t OFF_FFW2T  = OFF_FFW1T + 262144;
static const size_t WS_NEED    = OFF_FFW2T + 262144;

extern "C" void kernel_launch(void* const* d_in, const int* in_sizes, int n_in,
                              void* d_out, int out_size, void* d_ws, size_t ws_size,
                              hipStream_t stream) {
  if (ws_size < WS_NEED) return;  // workspace too small; fail validation cleanly

  const float* h       = (const float*)d_in[0];
  const float* gcn_w0  = (const float*)d_in[1];
  const float* gcn_b0  = (const float*)d_in[2];
  const float* gcn_w1  = (const float*)d_in[3];
  const float* gcn_b1  = (const float*)d_in[4];
  const float* bn_gcn0_g = (const float*)d_in[5];
  const float* bn_gcn0_b = (const float*)d_in[6];
  const float* bn_gcn1_g = (const float*)d_in[7];
  const float* bn_gcn1_b = (const float*)d_in[8];
  const float* gat_w0  = (const float*)d_in[9];
  const float* gat_al0 = (const float*)d_in[10];
  const float* gat_ar0 = (const float*)d_in[11];
  const float* gat_bias0 = (const float*)d_in[12];
  const float* gat_w1  = (const float*)d_in[13];
  const float* gat_al1 = (const float*)d_in[14];
  const float* gat_ar1 = (const float*)d_in[15];
  const float* gat_bias1 = (const float*)d_in[16];
  const float* bn_gat0_g = (const float*)d_in[17];
  const float* bn_gat0_b = (const float*)d_in[18];
  const float* bn_gat1_g = (const float*)d_in[19];
  const float* bn_gat1_b = (const float*)d_in[20];
  const float* gate_w  = (const float*)d_in[21];
  const float* gate_b  = (const float*)d_in[22];
  const float* qw      = (const float*)d_in[23];
  const float* kw      = (const float*)d_in[24];
  const float* vw      = (const float*)d_in[25];
  const float* ct_w    = (const float*)d_in[26];
  const float* ff_w1   = (const float*)d_in[27];
  const float* ff_b1   = (const float*)d_in[28];
  const float* ff_w2   = (const float*)d_in[29];
  const float* ff_b2   = (const float*)d_in[30];
  const float* ln_g    = (const float*)d_in[31];
  const float* ln_b    = (const float*)d_in[32];
  const int* srcv = (const int*)d_in[33];
  const int* dstv = (const int*)d_in[34];
  const int* gid  = (const int*)d_in[35];

  char* ws = (char*)d_ws;
  unsigned short* h_bf = (unsigned short*)(ws + OFF_BUFA);
  unsigned short* c01  = (unsigned short*)(ws + OFF_BUFA + 128000000);
  unsigned short* hg0  = (unsigned short*)(ws + OFF_BUFA + 179200000);
  unsigned short* ha0  = (unsigned short*)(ws + OFF_BUFA + 204800000);
  unsigned short* m1   = (unsigned short*)(ws + OFF_BUFA + 230400000);
  unsigned short* f1   = (unsigned short*)(ws + OFF_BUFA + 256000000);
  unsigned short* qkv  = (unsigned short*)(ws + OFF_BUFA);
  unsigned short* ff1o = (unsigned short*)(ws + OFF_BUFA);
  float* ff2o          = (float*)(ws + OFF_BUFA + 51200000);
  float* x2            = (float*)(ws + OFF_BUFA + 102400000);
  unsigned short* xcat = (unsigned short*)(ws + OFF_XCAT);
  float* glogit        = (float*)(ws + OFF_GLOGIT);
  float* mo            = (float*)(ws + OFF_GLOGIT);
  float* xf            = (float*)(ws + OFF_XF);
  unsigned short* xb   = (unsigned short*)(ws + OFF_XB);
  unsigned short* vs   = (unsigned short*)(ws + OFF_VS);
  float* x1f           = (float*)(ws + OFF_VS);
  unsigned short* x1b  = (unsigned short*)(ws + OFF_VS + 51200000);
  float* att           = (float*)(ws + OFF_ATT);
  float* alpha         = (float*)(ws + OFF_ALPHA);
  float* elr0          = (float*)(ws + OFF_ELR0);
  float* elr1          = (float*)(ws + OFF_ELR1);
  int* start   = (int*)(ws + OFF_START);
  int* deg_out = (int*)(ws + OFF_DEGO);
  int* deg_in  = (int*)(ws + OFF_DEGI);
  float* ns    = (float*)(ws + OFF_NS);
  float* nd    = (float*)(ws + OFF_ND);
  int* row_ptr = (int*)(ws + OFF_ROWP);
  int* fill    = (int*)(ws + OFF_FILL);
  int* csr_src = (int*)(ws + OFF_CSRS);
  unsigned short* w01t   = (unsigned short*)(ws + OFF_W01T);
  unsigned short* w1t    = (unsigned short*)(ws + OFF_W1T);
  unsigned short* w1gt   = (unsigned short*)(ws + OFF_W1GT);
  unsigned short* gatewt = (unsigned short*)(ws + OFF_GATEWT);
  unsigned short* wqkvt  = (unsigned short*)(ws + OFF_WQKVT);
  unsigned short* ctwt   = (unsigned short*)(ws + OFF_CTWT);
  unsigned short* ffw1t  = (unsigned short*)(ws + OFF_FFW1T);
  unsigned short* ffw2t  = (unsigned short*)(ws + OFF_FFW2T);

  float* out0 = (float*)d_out;            // readout [128,256]
  float* out1 = out0 + NG * HIDDEN;       // init_avg_h [128,1280]

  hipMemsetAsync(deg_out, 0, NN * 4, stream);
  hipMemsetAsync(deg_in, 0, NN * 4, stream);
  hipMemsetAsync(fill, 0, NN * 4, stream);

  // weight prep
  transpose_w_k<<<(1280 * 256 + 255) / 256, 256, 0, stream>>>(gcn_w0, w01t, 1280, 256);
  transpose_w_k<<<(1280 * 256 + 255) / 256, 256, 0, stream>>>(gat_w0, w01t + 256 * 1280, 1280, 256);
  transpose_w_k<<<(256 * 256 + 255) / 256, 256, 0, stream>>>(gcn_w1, w1t, 256, 256);
  transpose_w_k<<<(256 * 256 + 255) / 256, 256, 0, stream>>>(gat_w1, w1gt, 256, 256);
  transpose_w_k<<<(512 * 256 + 255) / 256, 256, 0, stream>>>(gate_w, gatewt, 512, 256);
  qkv_transpose_k<<<3072, 256, 0, stream>>>(qw, kw, vw, wqkvt);
  transpose_w_k<<<(1024 * 256 + 255) / 256, 256, 0, stream>>>(ct_w, ctwt, 1024, 256);
  transpose_w_k<<<(256 * 512 + 255) / 256, 256, 0, stream>>>(ff_w1, ffw1t, 256, 512);
  transpose_w_k<<<(512 * 256 + 255) / 256, 256, 0, stream>>>(ff_w2, ffw2t, 512, 256);

  cvt_bf16_k<<<(NN * DIN / 4 + 255) / 256, 256, 0, stream>>>(h, h_bf, NN * DIN / 4);

  // graph structure
  graph_bounds_k<<<(NN + 255) / 256, 256, 0, stream>>>(gid, start, NN);
  degrees_k<<<(NE + 255) / 256, 256, 0, stream>>>(srcv, dstv, deg_out, deg_in, NE);
  invsqrt_k<<<(NN + 255) / 256, 256, 0, stream>>>(deg_out, deg_in, ns, nd, NN);
  scan_k<<<1, 1024, 0, stream>>>(deg_in, row_ptr, NN);
  fill_csr_k<<<(NE + 255) / 256, 256, 0, stream>>>(srcv, dstv, row_ptr, fill, csr_src, NE);

  init_avg_k<<<dim3(NG, 5), 256, 0, stream>>>(h, start, out1);

  const int MB = (NN + 127) / 128;
  // GEMM1: h @ [gcn_w0 | gat_w0] -> c01 [N,512] bf16
  gemm_bf16<0><<<dim3(MB, 4), 256, 0, stream>>>(h_bf, w01t, c01, nullptr, NN, 1280, 512);
  // GCN layer 0
  gcn_agg_k<<<NN / 4, 256, 0, stream>>>(c01, 512, row_ptr, csr_src, ns, nd,
                                        gcn_b0, bn_gcn0_g, bn_gcn0_b, nullptr, 0, hg0, 256);
  // GAT layer 0
  elr_k<<<NN / 4, 256, 0, stream>>>(c01 + 256, 512, gat_al0, gat_ar0, elr0);
  gat_agg_k<<<NN / 4, 256, 0, stream>>>(c01 + 256, 512, row_ptr, csr_src, elr0,
                                        gat_bias0, bn_gat0_g, bn_gat0_b, nullptr, 0, ha0, 256);
  // GCN layer 1 (+residual hg0) -> xcat[:, :256]
  gemm_bf16<0><<<dim3(MB, 2), 256, 0, stream>>>(hg0, w1t, m1, nullptr, NN, 256, 256);
  gcn_agg_k<<<NN / 4, 256, 0, stream>>>(m1, 256, row_ptr, csr_src, ns, nd,
                                        gcn_b1, bn_gcn1_g, bn_gcn1_b, hg0, 256, xcat, 512);
  // GAT layer 1 (+residual ha0) -> xcat[:, 256:]
  gemm_bf16<0><<<dim3(MB, 2), 256, 0, stream>>>(ha0, w1gt, f1, nullptr, NN, 256, 256);
  elr_k<<<NN / 4, 256, 0, stream>>>(f1, 256, gat_al1, gat_ar1, elr1);
  gat_agg_k<<<NN / 4, 256, 0, stream>>>(f1, 256, row_ptr, csr_src, elr1,
                                        gat_bias1, bn_gat1_g, bn_gat1_b, ha0, 256, xcat + 256, 512);
  // gate
  gemm_bf16<1><<<dim3(MB, 2), 256, 0, stream>>>(xcat, gatewt, glogit, nullptr, NN, 512, 256);
  combine_k<<<NN / 4, 256, 0, stream>>>(glogit, gate_b, xcat, xf, xb);
  // transformer
  gemm_bf16<0><<<dim3(MB, 24), 256, 0, stream>>>(xb, wqkvt, qkv, nullptr, NN, 256, 3072);
  att_k<<<NN / 4, 256, 0, stream>>>(qkv, att);
  gsoftmax_k<<<NG, 256, 0, stream>>>(att, start, alpha);
  scalev_k<<<NN, 256, 0, stream>>>(qkv, alpha, vs);
  gemm_bf16<1><<<dim3(MB, 2), 256, 0, stream>>>(vs, ctwt, mo, nullptr, NN, 1024, 256);
  ln1_k<<<NN / 4, 256, 0, stream>>>(mo, xf, ln_g, ln_b, x1f, x1b);
  gemm_bf16<2><<<dim3(MB, 4), 256, 0, stream>>>(x1b, ffw1t, ff1o, ff_b1, NN, 256, 512);
  gemm_bf16<1><<<dim3(MB, 2), 256, 0, stream>>>(ff1o, ffw2t, ff2o, nullptr, NN, 512, 256);
  ln2_k<<<NN / 4, 256, 0, stream>>>(ff2o, ff_b2, x1f, ln_g, ln_b, x2);
  readout_k<<<NG, 256, 0, stream>>>(x2, start, out0);
}

// Round 2
// 1864.341 us; speedup vs baseline: 1.1001x; 1.1001x over previous
//
#include <hip/hip_runtime.h>

#define NN 50000
#define NE 800000
#define NG 128
#define DIN 1280
#define HIDDEN 256
#define BNS 0.9999950000374997f
#define ATT_SCALE 0.027950849718747373f
#define LN_EPS 1e-5f

typedef __attribute__((ext_vector_type(8))) short short8;
typedef __attribute__((ext_vector_type(4))) float floatx4;

__device__ __forceinline__ float b2f(unsigned short u) {
  return __uint_as_float(((unsigned int)u) << 16);
}
__device__ __forceinline__ unsigned short f2b(float f) {
  unsigned int x = __float_as_uint(f);
  x += 0x7fffu + ((x >> 16) & 1u);
  return (unsigned short)(x >> 16);
}

// ---------------- weight prep ----------------
// src [K][Nc] fp32 -> dst [Nc][K] bf16 (transposed, for GEMM B operand)
__global__ void transpose_w_k(const float* __restrict__ src, unsigned short* __restrict__ dst,
                              int K, int Nc) {
  int idx = blockIdx.x * 256 + threadIdx.x;
  if (idx >= K * Nc) return;
  int n = idx / K, k = idx % K;
  dst[idx] = f2b(src[(size_t)k * Nc + n]);
}

// M_h = qw_h @ kw_h^T; dst rows [0,1024): dst[col][d] = sum_e qw[h][d][e]*kw[h][dp][e]
// (col: h=col>>8, dp=col&255)
__global__ void mw_k(const float* __restrict__ qw, const float* __restrict__ kw,
                     unsigned short* __restrict__ dst) {
  int col = blockIdx.x;      // 0..1023
  int d = threadIdx.x;       // 0..255
  int hh = col >> 8, dp = col & 255;
  const float* qr = qw + ((size_t)hh * 256 + d) * 256;
  const float* kr = kw + ((size_t)hh * 256 + dp) * 256;
  float s = 0.f;
  for (int e = 0; e < 256; e += 4) {
    float4 a = *(const float4*)(qr + e);
    float4 b = *(const float4*)(kr + e);
    s += a.x * b.x + a.y * b.y + a.z * b.z + a.w * b.w;
  }
  dst[(size_t)col * 256 + d] = f2b(s);
}

// vw [4][256][256] -> dst rows [1024,2048): dst[1024+r][d] = vw[h][d][e2], h=r>>8, e2=r&255
__global__ void v_transpose_k(const float* __restrict__ vw, unsigned short* __restrict__ dst) {
  int idx = blockIdx.x * 256 + threadIdx.x;
  if (idx >= 1024 * 256) return;
  int r = idx >> 8;
  int d = idx & 255;
  int hh = r >> 8;
  int e2 = r & 255;
  dst[(size_t)(1024 + r) * 256 + d] = f2b(vw[((size_t)hh * 256 + d) * 256 + e2]);
}

// ---------------- fused h->bf16 conversion + per-graph sum (for init_avg_h) ----------------
// 50 rows per block; thread t covers columns t, t+256, ..., t+1024.
__global__ void cvt_avg_k(const float* __restrict__ h, const int* __restrict__ gid,
                          unsigned short* __restrict__ h_bf, float* __restrict__ out1) {
  int row0 = blockIdx.x * 50;
  int tid = threadIdx.x;
  float acc[5] = {0, 0, 0, 0, 0};
  int cur_g = gid[row0];
  for (int r = 0; r < 50; ++r) {
    int row = row0 + r;
    int g = gid[row];
    if (g != cur_g) {
#pragma unroll
      for (int j = 0; j < 5; ++j) {
        atomicAdd(&out1[(size_t)cur_g * DIN + j * 256 + tid], acc[j]);
        acc[j] = 0.f;
      }
      cur_g = g;
    }
#pragma unroll
    for (int j = 0; j < 5; ++j) {
      float v = h[(size_t)row * DIN + j * 256 + tid];
      acc[j] += v;
      h_bf[(size_t)row * DIN + j * 256 + tid] = f2b(v);
    }
  }
#pragma unroll
  for (int j = 0; j < 5; ++j)
    atomicAdd(&out1[(size_t)cur_g * DIN + j * 256 + tid], acc[j]);
}

__global__ void div_avg_k(const int* __restrict__ start, float* __restrict__ out1) {
  int idx = blockIdx.x * 256 + threadIdx.x;
  if (idx >= NG * DIN) return;
  int g = idx / DIN;
  float cnt = (float)(start[g + 1] - start[g]);
  if (cnt < 1.f) cnt = 1.f;
  out1[idx] /= cnt;
}

// ---------------- graph structure ----------------
__global__ void graph_bounds_k(const int* __restrict__ gid, int* __restrict__ start, int n) {
  int i = blockIdx.x * 256 + threadIdx.x;
  if (i >= n) return;
  int g = gid[i];
  if (i == 0) {
    for (int gg = 0; gg <= g; ++gg) start[gg] = 0;
  } else {
    int gp = gid[i - 1];
    for (int gg = gp + 1; gg <= g; ++gg) start[gg] = i;
  }
  if (i == n - 1) {
    for (int gg = g + 1; gg <= NG; ++gg) start[gg] = n;
  }
}

__global__ void degrees_k(const int* __restrict__ src, const int* __restrict__ dst,
                          int* __restrict__ deg_out, int* __restrict__ deg_in, int e) {
  int i = blockIdx.x * 256 + threadIdx.x;
  if (i >= e) return;
  atomicAdd(&deg_out[src[i]], 1);
  atomicAdd(&deg_in[dst[i]], 1);
}

__global__ void invsqrt_k(const int* __restrict__ deg_out, const int* __restrict__ deg_in,
                          float* __restrict__ ns, float* __restrict__ nd, int n) {
  int i = blockIdx.x * 256 + threadIdx.x;
  if (i >= n) return;
  int a = deg_out[i]; if (a < 1) a = 1;
  int b = deg_in[i];  if (b < 1) b = 1;
  ns[i] = rsqrtf((float)a);
  nd[i] = rsqrtf((float)b);
}

__global__ void scan_k(const int* __restrict__ deg, int* __restrict__ row_ptr, int n) {
  __shared__ int buf[1024];
  __shared__ int carry_s;
  int tid = threadIdx.x;
  if (tid == 0) carry_s = 0;
  __syncthreads();
  for (int base = 0; base < n; base += 1024) {
    int i = base + tid;
    int v = (i < n) ? deg[i] : 0;
    buf[tid] = v;
    __syncthreads();
    for (int off = 1; off < 1024; off <<= 1) {
      int t = (tid >= off) ? buf[tid - off] : 0;
      __syncthreads();
      buf[tid] += t;
      __syncthreads();
    }
    int carry = carry_s;
    if (i < n) row_ptr[i] = carry + buf[tid] - v;
    __syncthreads();
    if (tid == 1023) carry_s = carry + buf[1023];
    __syncthreads();
  }
  if (tid == 0) row_ptr[n] = carry_s;
}

__global__ void fill_csr_k(const int* __restrict__ src, const int* __restrict__ dst,
                           const int* __restrict__ row_ptr, int* __restrict__ fill,
                           int* __restrict__ csr_src, int e) {
  int i = blockIdx.x * 256 + threadIdx.x;
  if (i >= e) return;
  int d = dst[i];
  int pos = row_ptr[d] + atomicAdd(&fill[d], 1);
  csr_src[pos] = src[i];
}

// ---------------- bf16 MFMA GEMM ----------------
// C[M,Nc] = A[M,K](bf16,row-major) * Bt[Nc,K](bf16, = W^T)
// MODE 0: bf16 out; 1: fp32 out; 2: +bias, relu, bf16 out
template <int MODE>
__global__ __launch_bounds__(256, 2) void gemm_bf16(const unsigned short* __restrict__ A,
                                                    const unsigned short* __restrict__ Bt,
                                                    void* __restrict__ Cout,
                                                    const float* __restrict__ bias,
                                                    int M, int K, int Nc) {
  __shared__ unsigned short lA[8192];  // [kb 0..7][128 rows][8], chunk index swizzled by ^kb
  __shared__ unsigned short lB[8192];
  const int tid = threadIdx.x;
  const int m0 = blockIdx.x * 128;
  const int n0 = blockIdx.y * 128;
  const int w = tid >> 6;
  const int lane = tid & 63;
  const int wr = (w >> 1) * 64;
  const int wc = (w & 1) * 64;
  const int quad = lane >> 4;
  const int l15 = lane & 15;
  const int js = tid & 7;
  const int mbase = tid >> 3;

  floatx4 acc[4][4];
#pragma unroll
  for (int i = 0; i < 4; ++i)
#pragma unroll
    for (int j = 0; j < 4; ++j) acc[i][j] = (floatx4)0.0f;

  for (int k0 = 0; k0 < K; k0 += 64) {
    __syncthreads();
#pragma unroll
    for (int it = 0; it < 4; ++it) {
      int m = it * 32 + mbase;
      int gm = m0 + m;
      if (gm >= M) gm = M - 1;
      uint4 va = *(const uint4*)(A + (size_t)gm * K + k0 + js * 8);
      int ci_ = js * 128 + (m ^ js);
      *(uint4*)(lA + ci_ * 8) = va;
      int gn = n0 + m;
      uint4 vb = *(const uint4*)(Bt + (size_t)gn * K + k0 + js * 8);
      *(uint4*)(lB + ci_ * 8) = vb;
    }
    __syncthreads();
#pragma unroll
    for (int ks = 0; ks < 2; ++ks) {
      int kb = ks * 4 + quad;
      short8 af[4], bfr[4];
#pragma unroll
      for (int ri = 0; ri < 4; ++ri) {
        int r = wr + ri * 16 + l15;
        af[ri] = *(const short8*)(lA + (kb * 128 + (r ^ kb)) * 8);
      }
#pragma unroll
      for (int ci = 0; ci < 4; ++ci) {
        int c = wc + ci * 16 + l15;
        bfr[ci] = *(const short8*)(lB + (kb * 128 + (c ^ kb)) * 8);
      }
#pragma unroll
      for (int ri = 0; ri < 4; ++ri)
#pragma unroll
        for (int ci = 0; ci < 4; ++ci)
          acc[ri][ci] = __builtin_amdgcn_mfma_f32_16x16x32_bf16(af[ri], bfr[ci], acc[ri][ci], 0, 0, 0);
    }
  }
#pragma unroll
  for (int ri = 0; ri < 4; ++ri) {
    int row = m0 + wr + ri * 16 + quad * 4;
#pragma unroll
    for (int ci = 0; ci < 4; ++ci) {
      int col = n0 + wc + ci * 16 + l15;
      float bv = (MODE == 2) ? bias[col] : 0.f;
#pragma unroll
      for (int r = 0; r < 4; ++r) {
        if (row + r < M) {
          float v = acc[ri][ci][r];
          if (MODE == 2) { v += bv; v = fmaxf(v, 0.f); }
          if (MODE == 1)
            ((float*)Cout)[(size_t)(row + r) * Nc + col] = v;
          else
            ((unsigned short*)Cout)[(size_t)(row + r) * Nc + col] = f2b(v);
        }
      }
    }
  }
}

// ---------------- GCN aggregation: out = act(bn(sum_e ns[u]*m[u] * nd + bias)) [+resid] ----------------
__global__ void gcn_agg_k(const unsigned short* __restrict__ m, int ldm,
                          const int* __restrict__ row_ptr, const int* __restrict__ csr_src,
                          const float* __restrict__ ns, const float* __restrict__ nd,
                          const float* __restrict__ bias,
                          const float* __restrict__ bng, const float* __restrict__ bnb,
                          const unsigned short* __restrict__ resid, int ldr,
                          unsigned short* __restrict__ out, int ldo) {
  int node = blockIdx.x * 4 + (threadIdx.x >> 6);
  if (node >= NN) return;
  int lane = threadIdx.x & 63;
  int s = row_ptr[node], e = row_ptr[node + 1];
  float a0 = 0, a1 = 0, a2 = 0, a3 = 0;
  for (int i = s; i < e; ++i) {
    int u = csr_src[i];
    float w = ns[u];
    ushort4 v = *(const ushort4*)(m + (size_t)u * ldm + lane * 4);
    a0 += w * b2f(v.x); a1 += w * b2f(v.y); a2 += w * b2f(v.z); a3 += w * b2f(v.w);
  }
  float ndv = nd[node];
  int col = lane * 4;
  float vals[4] = {a0, a1, a2, a3};
  ushort4 o;
#pragma unroll
  for (int c = 0; c < 4; ++c) {
    float v = vals[c] * ndv + bias[col + c];
    v = bng[col + c] * v * BNS + bnb[col + c];
    v = fmaxf(v, 0.f);
    if (resid) v += b2f(resid[(size_t)node * ldr + col + c]);
    ((unsigned short*)&o)[c] = f2b(v);
  }
  *(ushort4*)(out + (size_t)node * ldo + col) = o;
}

// ---------------- GAT el/er ----------------
__global__ void elr_k(const unsigned short* __restrict__ f, int ldf,
                      const float* __restrict__ al, const float* __restrict__ ar,
                      float* __restrict__ elr) {
  int node = blockIdx.x * 4 + (threadIdx.x >> 6);
  if (node >= NN) return;
  int lane = threadIdx.x & 63;
  int head = lane >> 4;
  int col = lane * 4;
  int dcol = col & 63;
  ushort4 v = *(const ushort4*)(f + (size_t)node * ldf + col);
  float pl = 0, pr = 0;
#pragma unroll
  for (int c = 0; c < 4; ++c) {
    float x = b2f(((unsigned short*)&v)[c]);
    pl += x * al[head * 64 + dcol + c];
    pr += x * ar[head * 64 + dcol + c];
  }
#pragma unroll
  for (int off = 1; off < 16; off <<= 1) {
    pl += __shfl_xor(pl, off);
    pr += __shfl_xor(pr, off);
  }
  if ((lane & 15) == 0) {
    elr[(size_t)node * 8 + head] = pl;
    elr[(size_t)node * 8 + 4 + head] = pr;
  }
}

// ---------------- GAT aggregation (edge softmax + weighted sum + bn + elu [+resid]) ----------------
__global__ void gat_agg_k(const unsigned short* __restrict__ f, int ldf,
                          const int* __restrict__ row_ptr, const int* __restrict__ csr_src,
                          const float* __restrict__ elr,
                          const float* __restrict__ bias,
                          const float* __restrict__ bng, const float* __restrict__ bnb,
                          const unsigned short* __restrict__ resid, int ldr,
                          unsigned short* __restrict__ out, int ldo) {
  int node = blockIdx.x * 4 + (threadIdx.x >> 6);
  if (node >= NN) return;
  int lane = threadIdx.x & 63;
  int s = row_ptr[node], e = row_ptr[node + 1];
  float4 er = *(const float4*)(elr + (size_t)node * 8 + 4);
  float m0 = -1e30f, m1 = -1e30f, m2 = -1e30f, m3 = -1e30f;
  for (int i = s + lane; i < e; i += 64) {
    int u = csr_src[i];
    float4 el = *(const float4*)(elr + (size_t)u * 8);
    float t;
    t = el.x + er.x; t = t > 0.f ? t : 0.2f * t; m0 = fmaxf(m0, t);
    t = el.y + er.y; t = t > 0.f ? t : 0.2f * t; m1 = fmaxf(m1, t);
    t = el.z + er.z; t = t > 0.f ? t : 0.2f * t; m2 = fmaxf(m2, t);
    t = el.w + er.w; t = t > 0.f ? t : 0.2f * t; m3 = fmaxf(m3, t);
  }
#pragma unroll
  for (int off = 1; off < 64; off <<= 1) {
    m0 = fmaxf(m0, __shfl_xor(m0, off));
    m1 = fmaxf(m1, __shfl_xor(m1, off));
    m2 = fmaxf(m2, __shfl_xor(m2, off));
    m3 = fmaxf(m3, __shfl_xor(m3, off));
  }
  float s0 = 0, s1 = 0, s2 = 0, s3 = 0;
  for (int i = s + lane; i < e; i += 64) {
    int u = csr_src[i];
    float4 el = *(const float4*)(elr + (size_t)u * 8);
    float t;
    t = el.x + er.x; t = t > 0.f ? t : 0.2f * t; s0 += expf(t - m0);
    t = el.y + er.y; t = t > 0.f ? t : 0.2f * t; s1 += expf(t - m1);
    t = el.z + er.z; t = t > 0.f ? t : 0.2f * t; s2 += expf(t - m2);
    t = el.w + er.w; t = t > 0.f ? t : 0.2f * t; s3 += expf(t - m3);
  }
#pragma unroll
  for (int off = 1; off < 64; off <<= 1) {
    s0 += __shfl_xor(s0, off);
    s1 += __shfl_xor(s1, off);
    s2 += __shfl_xor(s2, off);
    s3 += __shfl_xor(s3, off);
  }
  int head = lane >> 4;
  float erh = head == 0 ? er.x : head == 1 ? er.y : head == 2 ? er.z : er.w;
  float mh = head == 0 ? m0 : head == 1 ? m1 : head == 2 ? m2 : m3;
  float sh = head == 0 ? s0 : head == 1 ? s1 : head == 2 ? s2 : s3;
  float inv_sh = (sh > 0.f) ? 1.f / sh : 0.f;
  float a0 = 0, a1 = 0, a2 = 0, a3 = 0;
  for (int i = s; i < e; ++i) {
    int u = csr_src[i];
    float t = elr[(size_t)u * 8 + head] + erh;
    t = t > 0.f ? t : 0.2f * t;
    float wgt = expf(t - mh) * inv_sh;
    ushort4 v = *(const ushort4*)(f + (size_t)u * ldf + lane * 4);
    a0 += wgt * b2f(v.x); a1 += wgt * b2f(v.y); a2 += wgt * b2f(v.z); a3 += wgt * b2f(v.w);
  }
  int col = lane * 4;
  float vals[4] = {a0, a1, a2, a3};
  ushort4 o;
#pragma unroll
  for (int c = 0; c < 4; ++c) {
    float v = vals[c] + bias[col + c];
    v = bng[col + c] * v * BNS + bnb[col + c];
    v = (v > 0.f) ? v : (expf(v) - 1.f);
    if (resid) v += b2f(resid[(size_t)node * ldr + col + c]);
    ((unsigned short*)&o)[c] = f2b(v);
  }
  *(ushort4*)(out + (size_t)node * ldo + col) = o;
}

// ---------------- gate combine ----------------
__global__ void combine_k(const float* __restrict__ glogit, const float* __restrict__ gate_b,
                          const unsigned short* __restrict__ xcat,
                          float* __restrict__ xf, unsigned short* __restrict__ xb) {
  int idx = blockIdx.x * 256 + threadIdx.x;
  if (idx >= NN * 64) return;
  int node = idx >> 6;
  int c = (idx & 63) * 4;
  float4 gl = *(const float4*)(glogit + (size_t)node * HIDDEN + c);
  ushort4 hgv = *(const ushort4*)(xcat + (size_t)node * 512 + c);
  ushort4 hav = *(const ushort4*)(xcat + (size_t)node * 512 + 256 + c);
  float4 o;
  float g;
  g = 1.f / (1.f + expf(-(gl.x + gate_b[c + 0]))); o.x = g * b2f(hgv.x) + (1.f - g) * b2f(hav.x);
  g = 1.f / (1.f + expf(-(gl.y + gate_b[c + 1]))); o.y = g * b2f(hgv.y) + (1.f - g) * b2f(hav.y);
  g = 1.f / (1.f + expf(-(gl.z + gate_b[c + 2]))); o.z = g * b2f(hgv.z) + (1.f - g) * b2f(hav.z);
  g = 1.f / (1.f + expf(-(gl.w + gate_b[c + 3]))); o.w = g * b2f(hgv.w) + (1.f - g) * b2f(hav.w);
  *(float4*)(xf + (size_t)node * HIDDEN + c) = o;
  ushort4 ob;
  ob.x = f2b(o.x); ob.y = f2b(o.y); ob.z = f2b(o.z); ob.w = f2b(o.w);
  *(ushort4*)(xb + (size_t)node * HIDDEN + c) = ob;
}

// ---------------- attention scores: att[n,h] = (y_h[n,:] . x[n,:]) * scale ----------------
__global__ void att2_k(const unsigned short* __restrict__ yv, const unsigned short* __restrict__ xb,
                       float* __restrict__ att) {
  int node = blockIdx.x * 4 + (threadIdx.x >> 6);
  if (node >= NN) return;
  int lane = threadIdx.x & 63;
  const unsigned short* y = yv + (size_t)node * 2048;
  ushort4 xv = *(const ushort4*)(xb + (size_t)node * 256 + lane * 4);
  float x0 = b2f(xv.x), x1 = b2f(xv.y), x2 = b2f(xv.z), x3 = b2f(xv.w);
#pragma unroll
  for (int h = 0; h < 4; ++h) {
    ushort4 yv4 = *(const ushort4*)(y + h * 256 + lane * 4);
    float p = b2f(yv4.x) * x0 + b2f(yv4.y) * x1 + b2f(yv4.z) * x2 + b2f(yv4.w) * x3;
#pragma unroll
    for (int off = 1; off < 64; off <<= 1) p += __shfl_xor(p, off);
    if (lane == 0) att[(size_t)node * 4 + h] = p * ATT_SCALE;
  }
}

// ---------------- per-graph node softmax ----------------
__global__ void gsoftmax_k(const float* __restrict__ att, const int* __restrict__ start,
                           float* __restrict__ alpha) {
  int g = blockIdx.x;
  int s = start[g], e = start[g + 1];
  int tid = threadIdx.x;
  __shared__ float red[256];
  __shared__ float mh[4], sh[4];
  float lm[4] = {-1e30f, -1e30f, -1e30f, -1e30f};
  for (int i = s + tid; i < e; i += 256) {
    float4 a = *(const float4*)(att + (size_t)i * 4);
    lm[0] = fmaxf(lm[0], a.x); lm[1] = fmaxf(lm[1], a.y);
    lm[2] = fmaxf(lm[2], a.z); lm[3] = fmaxf(lm[3], a.w);
  }
#pragma unroll
  for (int h = 0; h < 4; ++h) {
    red[tid] = lm[h]; __syncthreads();
    for (int off = 128; off > 0; off >>= 1) {
      if (tid < off) red[tid] = fmaxf(red[tid], red[tid + off]);
      __syncthreads();
    }
    if (tid == 0) mh[h] = red[0];
    __syncthreads();
  }
  float ls[4] = {0, 0, 0, 0};
  for (int i = s + tid; i < e; i += 256) {
    float4 a = *(const float4*)(att + (size_t)i * 4);
    ls[0] += expf(a.x - mh[0]); ls[1] += expf(a.y - mh[1]);
    ls[2] += expf(a.z - mh[2]); ls[3] += expf(a.w - mh[3]);
  }
#pragma unroll
  for (int h = 0; h < 4; ++h) {
    red[tid] = ls[h]; __syncthreads();
    for (int off = 128; off > 0; off >>= 1) {
      if (tid < off) red[tid] += red[tid + off];
      __syncthreads();
    }
    if (tid == 0) sh[h] = red[0];
    __syncthreads();
  }
  for (int i = s + tid; i < e; i += 256) {
    float4 a = *(const float4*)(att + (size_t)i * 4);
    float4 o;
    o.x = expf(a.x - mh[0]) / sh[0];
    o.y = expf(a.y - mh[1]) / sh[1];
    o.z = expf(a.z - mh[2]) / sh[2];
    o.w = expf(a.w - mh[3]) / sh[3];
    *(float4*)(alpha + (size_t)i * 4) = o;
  }
}

// ---------------- scale V by alpha (V lives at yv[:,1024:2048]) ----------------
__global__ void scalev_k(const unsigned short* __restrict__ yv, const float* __restrict__ alpha,
                         unsigned short* __restrict__ vs) {
  int idx = blockIdx.x * 256 + threadIdx.x;
  if (idx >= NN * 256) return;
  int node = idx >> 8;
  int c = (idx & 255) * 4;
  int h = c >> 8;
  float a = alpha[(size_t)node * 4 + h];
  ushort4 v = *(const ushort4*)(yv + (size_t)node * 2048 + 1024 + c);
  ushort4 o;
  o.x = f2b(b2f(v.x) * a); o.y = f2b(b2f(v.y) * a);
  o.z = f2b(b2f(v.z) * a); o.w = f2b(b2f(v.w) * a);
  *(ushort4*)(vs + (size_t)node * 1024 + c) = o;
}

// ---------------- LayerNorms ----------------
__global__ void ln1_k(const float* __restrict__ mo, const float* __restrict__ x,
                      const float* __restrict__ g, const float* __restrict__ b,
                      float* __restrict__ x1f, unsigned short* __restrict__ x1b) {
  int node = blockIdx.x * 4 + (threadIdx.x >> 6);
  if (node >= NN) return;
  int lane = threadIdx.x & 63;
  int c = lane * 4;
  float4 a = *(const float4*)(mo + (size_t)node * HIDDEN + c);
  float4 xx = *(const float4*)(x + (size_t)node * HIDDEN + c);
  float v0 = a.x + xx.x, v1 = a.y + xx.y, v2 = a.z + xx.z, v3 = a.w + xx.w;
  float sm = v0 + v1 + v2 + v3;
#pragma unroll
  for (int off = 1; off < 64; off <<= 1) sm += __shfl_xor(sm, off);
  float mu = sm * (1.f / 256.f);
  float d0 = v0 - mu, d1 = v1 - mu, d2 = v2 - mu, d3 = v3 - mu;
  float sq = d0 * d0 + d1 * d1 + d2 * d2 + d3 * d3;
#pragma unroll
  for (int off = 1; off < 64; off <<= 1) sq += __shfl_xor(sq, off);
  float inv = rsqrtf(sq * (1.f / 256.f) + LN_EPS);
  float4 o;
  o.x = g[c + 0] * d0 * inv + b[c + 0];
  o.y = g[c + 1] * d1 * inv + b[c + 1];
  o.z = g[c + 2] * d2 * inv + b[c + 2];
  o.w = g[c + 3] * d3 * inv + b[c + 3];
  *(float4*)(x1f + (size_t)node * HIDDEN + c) = o;
  ushort4 ob;
  ob.x = f2b(o.x); ob.y = f2b(o.y); ob.z = f2b(o.z); ob.w = f2b(o.w);
  *(ushort4*)(x1b + (size_t)node * HIDDEN + c) = ob;
}

__global__ void ln2_k(const float* __restrict__ ff2o, const float* __restrict__ ffb2,
                      const float* __restrict__ x1f,
                      const float* __restrict__ g, const float* __restrict__ b,
                      float* __restrict__ x2) {
  int node = blockIdx.x * 4 + (threadIdx.x >> 6);
  if (node >= NN) return;
  int lane = threadIdx.x & 63;
  int c = lane * 4;
  float4 a = *(const float4*)(ff2o + (size_t)node * HIDDEN + c);
  float4 xx = *(const float4*)(x1f + (size_t)node * HIDDEN + c);
  float v0 = a.x + ffb2[c + 0] + xx.x, v1 = a.y + ffb2[c + 1] + xx.y;
  float v2 = a.z + ffb2[c + 2] + xx.z, v3 = a.w + ffb2[c + 3] + xx.w;
  float sm = v0 + v1 + v2 + v3;
#pragma unroll
  for (int off = 1; off < 64; off <<= 1) sm += __shfl_xor(sm, off);
  float mu = sm * (1.f / 256.f);
  float d0 = v0 - mu, d1 = v1 - mu, d2 = v2 - mu, d3 = v3 - mu;
  float sq = d0 * d0 + d1 * d1 + d2 * d2 + d3 * d3;
#pragma unroll
  for (int off = 1; off < 64; off <<= 1) sq += __shfl_xor(sq, off);
  float inv = rsqrtf(sq * (1.f / 256.f) + LN_EPS);
  float4 o;
  o.x = g[c + 0] * d0 * inv + b[c + 0];
  o.y = g[c + 1] * d1 * inv + b[c + 1];
  o.z = g[c + 2] * d2 * inv + b[c + 2];
  o.w = g[c + 3] * d3 * inv + b[c + 3];
  *(float4*)(x2 + (size_t)node * HIDDEN + c) = o;
}

// ---------------- readout (output 0) ----------------
__global__ void readout_k(const float* __restrict__ x2, const int* __restrict__ start,
                          float* __restrict__ out0) {
  int g = blockIdx.x;
  int c = threadIdx.x;
  float acc = 0.f;
  for (int i = start[g]; i < start[g + 1]; ++i) acc += x2[(size_t)i * HIDDEN + c];
  out0[(size_t)g * HIDDEN + c] = acc;
}

// ---------------- workspace layout (bytes) ----------------
// bufA is phase-overlapped: phase1 {h_bf,c01,hg0,ha0,m1,f1} / phase2 {yv} / phase3 {ff1o,ff2o,x2}
static const size_t OFF_BUFA   = 0;
static const size_t OFF_XCAT   = 307200000;
static const size_t OFF_GLOGIT = OFF_XCAT + 51200000;   // also mo
static const size_t OFF_XF     = OFF_GLOGIT + 51200000;
static const size_t OFF_XB     = OFF_XF + 51200000;
static const size_t OFF_VS     = OFF_XB + 25600000;     // also x1f (+0) and x1b (+51200000)
static const size_t OFF_ATT    = OFF_VS + 102400000;
static const size_t OFF_ALPHA  = OFF_ATT + 800000;
static const size_t OFF_ELR0   = OFF_ALPHA + 800000;
static const size_t OFF_ELR1   = OFF_ELR0 + 1600000;
static const size_t OFF_START  = OFF_ELR1 + 1600000;
static const size_t OFF_DEGO   = OFF_START + 1024;
static const size_t OFF_DEGI   = OFF_DEGO + 200704;
static const size_t OFF_NS     = OFF_DEGI + 200704;
static const size_t OFF_ND     = OFF_NS + 200704;
static const size_t OFF_ROWP   = OFF_ND + 200704;
static const size_t OFF_FILL   = OFF_ROWP + 200704;
static const size_t OFF_CSRS   = OFF_FILL + 200704;
static const size_t OFF_W01T   = OFF_CSRS + 3200000;
static const size_t OFF_W1T    = OFF_W01T + 1310720;
static const size_t OFF_W1GT   = OFF_W1T + 131072;
static const size_t OFF_GATEWT = OFF_W1GT + 131072;
static const size_t OFF_WMVT   = OFF_GATEWT + 262144;   // [2048][256] bf16 = 1 MiB
static const size_t OFF_CTWT   = OFF_WMVT + 1572864;
static const size_t OFF_FFW1T  = OFF_CTWT + 524288;
static const size_t OFF_FFW2T  = OFF_FFW1T + 262144;
static const size_t WS_NEED    = OFF_FFW2T + 262144;

extern "C" void kernel_launch(void* const* d_in, const int* in_sizes, int n_in,
                              void* d_out, int out_size, void* d_ws, size_t ws_size,
                              hipStream_t stream) {
  if (ws_size < WS_NEED) return;  // workspace too small; fail validation cleanly

  const float* h       = (const float*)d_in[0];
  const float* gcn_w0  = (const float*)d_in[1];
  const float* gcn_b0  = (const float*)d_in[2];
  const float* gcn_w1  = (const float*)d_in[3];
  const float* gcn_b1  = (const float*)d_in[4];
  const float* bn_gcn0_g = (const float*)d_in[5];
  const float* bn_gcn0_b = (const float*)d_in[6];
  const float* bn_gcn1_g = (const float*)d_in[7];
  const float* bn_gcn1_b = (const float*)d_in[8];
  const float* gat_w0  = (const float*)d_in[9];
  const float* gat_al0 = (const float*)d_in[10];
  const float* gat_ar0 = (const float*)d_in[11];
  const float* gat_bias0 = (const float*)d_in[12];
  const float* gat_w1  = (const float*)d_in[13];
  const float* gat_al1 = (const float*)d_in[14];
  const float* gat_ar1 = (const float*)d_in[15];
  const float* gat_bias1 = (const float*)d_in[16];
  const float* bn_gat0_g = (const float*)d_in[17];
  const float* bn_gat0_b = (const float*)d_in[18];
  const float* bn_gat1_g = (const float*)d_in[19];
  const float* bn_gat1_b = (const float*)d_in[20];
  const float* gate_w  = (const float*)d_in[21];
  const float* gate_b  = (const float*)d_in[22];
  const float* qw      = (const float*)d_in[23];
  const float* kw      = (const float*)d_in[24];
  const float* vw      = (const float*)d_in[25];
  const float* ct_w    = (const float*)d_in[26];
  const float* ff_w1   = (const float*)d_in[27];
  const float* ff_b1   = (const float*)d_in[28];
  const float* ff_w2   = (const float*)d_in[29];
  const float* ff_b2   = (const float*)d_in[30];
  const float* ln_g    = (const float*)d_in[31];
  const float* ln_b    = (const float*)d_in[32];
  const int* srcv = (const int*)d_in[33];
  const int* dstv = (const int*)d_in[34];
  const int* gid  = (const int*)d_in[35];

  char* ws = (char*)d_ws;
  unsigned short* h_bf = (unsigned short*)(ws + OFF_BUFA);
  unsigned short* c01  = (unsigned short*)(ws + OFF_BUFA + 128000000);
  unsigned short* hg0  = (unsigned short*)(ws + OFF_BUFA + 179200000);
  unsigned short* ha0  = (unsigned short*)(ws + OFF_BUFA + 204800000);
  unsigned short* m1   = (unsigned short*)(ws + OFF_BUFA + 230400000);
  unsigned short* f1   = (unsigned short*)(ws + OFF_BUFA + 256000000);
  unsigned short* yv   = (unsigned short*)(ws + OFF_BUFA);
  unsigned short* ff1o = (unsigned short*)(ws + OFF_BUFA);
  float* ff2o          = (float*)(ws + OFF_BUFA + 51200000);
  float* x2            = (float*)(ws + OFF_BUFA + 102400000);
  unsigned short* xcat = (unsigned short*)(ws + OFF_XCAT);
  float* glogit        = (float*)(ws + OFF_GLOGIT);
  float* mo            = (float*)(ws + OFF_GLOGIT);
  float* xf            = (float*)(ws + OFF_XF);
  unsigned short* xb   = (unsigned short*)(ws + OFF_XB);
  unsigned short* vs   = (unsigned short*)(ws + OFF_VS);
  float* x1f           = (float*)(ws + OFF_VS);
  unsigned short* x1b  = (unsigned short*)(ws + OFF_VS + 51200000);
  float* att           = (float*)(ws + OFF_ATT);
  float* alpha         = (float*)(ws + OFF_ALPHA);
  float* elr0          = (float*)(ws + OFF_ELR0);
  float* elr1          = (float*)(ws + OFF_ELR1);
  int* start   = (int*)(ws + OFF_START);
  int* deg_out = (int*)(ws + OFF_DEGO);
  int* deg_in  = (int*)(ws + OFF_DEGI);
  float* ns    = (float*)(ws + OFF_NS);
  float* nd    = (float*)(ws + OFF_ND);
  int* row_ptr = (int*)(ws + OFF_ROWP);
  int* fill    = (int*)(ws + OFF_FILL);
  int* csr_src = (int*)(ws + OFF_CSRS);
  unsigned short* w01t   = (unsigned short*)(ws + OFF_W01T);
  unsigned short* w1t    = (unsigned short*)(ws + OFF_W1T);
  unsigned short* w1gt   = (unsigned short*)(ws + OFF_W1GT);
  unsigned short* gatewt = (unsigned short*)(ws + OFF_GATEWT);
  unsigned short* wmvt   = (unsigned short*)(ws + OFF_WMVT);
  unsigned short* ctwt   = (unsigned short*)(ws + OFF_CTWT);
  unsigned short* ffw1t  = (unsigned short*)(ws + OFF_FFW1T);
  unsigned short* ffw2t  = (unsigned short*)(ws + OFF_FFW2T);

  float* out0 = (float*)d_out;            // readout [128,256]
  float* out1 = out0 + NG * HIDDEN;       // init_avg_h [128,1280]

  hipMemsetAsync(deg_out, 0, NN * 4, stream);
  hipMemsetAsync(deg_in, 0, NN * 4, stream);
  hipMemsetAsync(fill, 0, NN * 4, stream);
  hipMemsetAsync(out1, 0, NG * DIN * 4, stream);

  // weight prep
  transpose_w_k<<<(1280 * 256 + 255) / 256, 256, 0, stream>>>(gcn_w0, w01t, 1280, 256);
  transpose_w_k<<<(1280 * 256 + 255) / 256, 256, 0, stream>>>(gat_w0, w01t + 256 * 1280, 1280, 256);
  transpose_w_k<<<(256 * 256 + 255) / 256, 256, 0, stream>>>(gcn_w1, w1t, 256, 256);
  transpose_w_k<<<(256 * 256 + 255) / 256, 256, 0, stream>>>(gat_w1, w1gt, 256, 256);
  transpose_w_k<<<(512 * 256 + 255) / 256, 256, 0, stream>>>(gate_w, gatewt, 512, 256);
  mw_k<<<1024, 256, 0, stream>>>(qw, kw, wmvt);
  v_transpose_k<<<1024, 256, 0, stream>>>(vw, wmvt);
  transpose_w_k<<<(1024 * 256 + 255) / 256, 256, 0, stream>>>(ct_w, ctwt, 1024, 256);
  transpose_w_k<<<(256 * 512 + 255) / 256, 256, 0, stream>>>(ff_w1, ffw1t, 256, 512);
  transpose_w_k<<<(512 * 256 + 255) / 256, 256, 0, stream>>>(ff_w2, ffw2t, 512, 256);

  // graph structure
  graph_bounds_k<<<(NN + 255) / 256, 256, 0, stream>>>(gid, start, NN);
  degrees_k<<<(NE + 255) / 256, 256, 0, stream>>>(srcv, dstv, deg_out, deg_in, NE);
  invsqrt_k<<<(NN + 255) / 256, 256, 0, stream>>>(deg_out, deg_in, ns, nd, NN);
  scan_k<<<1, 1024, 0, stream>>>(deg_in, row_ptr, NN);
  fill_csr_k<<<(NE + 255) / 256, 256, 0, stream>>>(srcv, dstv, row_ptr, fill, csr_src, NE);

  // fused h->bf16 + per-graph sums, then divide by counts
  cvt_avg_k<<<NN / 50, 256, 0, stream>>>(h, gid, h_bf, out1);
  div_avg_k<<<(NG * DIN + 255) / 256, 256, 0, stream>>>(start, out1);

  const int MB = (NN + 127) / 128;
  // GEMM1: h @ [gcn_w0 | gat_w0] -> c01 [N,512] bf16
  gemm_bf16<0><<<dim3(MB, 4), 256, 0, stream>>>(h_bf, w01t, c01, nullptr, NN, 1280, 512);
  // GCN layer 0
  gcn_agg_k<<<NN / 4, 256, 0, stream>>>(c01, 512, row_ptr, csr_src, ns, nd,
                                        gcn_b0, bn_gcn0_g, bn_gcn0_b, nullptr, 0, hg0, 256);
  // GAT layer 0
  elr_k<<<NN / 4, 256, 0, stream>>>(c01 + 256, 512, gat_al0, gat_ar0, elr0);
  gat_agg_k<<<NN / 4, 256, 0, stream>>>(c01 + 256, 512, row_ptr, csr_src, elr0,
                                        gat_bias0, bn_gat0_g, bn_gat0_b, nullptr, 0, ha0, 256);
  // GCN layer 1 (+residual hg0) -> xcat[:, :256]
  gemm_bf16<0><<<dim3(MB, 2), 256, 0, stream>>>(hg0, w1t, m1, nullptr, NN, 256, 256);
  gcn_agg_k<<<NN / 4, 256, 0, stream>>>(m1, 256, row_ptr, csr_src, ns, nd,
                                        gcn_b1, bn_gcn1_g, bn_gcn1_b, hg0, 256, xcat, 512);
  // GAT layer 1 (+residual ha0) -> xcat[:, 256:]
  gemm_bf16<0><<<dim3(MB, 2), 256, 0, stream>>>(ha0, w1gt, f1, nullptr, NN, 256, 256);
  elr_k<<<NN / 4, 256, 0, stream>>>(f1, 256, gat_al1, gat_ar1, elr1);
  gat_agg_k<<<NN / 4, 256, 0, stream>>>(f1, 256, row_ptr, csr_src, elr1,
                                        gat_bias1, bn_gat1_g, bn_gat1_b, ha0, 256, xcat + 256, 512);
  // gate
  gemm_bf16<1><<<dim3(MB, 2), 256, 0, stream>>>(xcat, gatewt, glogit, nullptr, NN, 512, 256);
  combine_k<<<NN / 4, 256, 0, stream>>>(glogit, gate_b, xcat, xf, xb);
  // transformer: yv = xb @ [M heads | vw heads]  (q.k folded into M = Wq Wk^T)
  gemm_bf16<0><<<dim3(MB, 16), 256, 0, stream>>>(xb, wmvt, yv, nullptr, NN, 256, 2048);
  att2_k<<<NN / 4, 256, 0, stream>>>(yv, xb, att);
  gsoftmax_k<<<NG, 256, 0, stream>>>(att, start, alpha);
  scalev_k<<<NN, 256, 0, stream>>>(yv, alpha, vs);
  gemm_bf16<1><<<dim3(MB, 2), 256, 0, stream>>>(vs, ctwt, mo, nullptr, NN, 1024, 256);
  ln1_k<<<NN / 4, 256, 0, stream>>>(mo, xf, ln_g, ln_b, x1f, x1b);
  gemm_bf16<2><<<dim3(MB, 4), 256, 0, stream>>>(x1b, ffw1t, ff1o, ff_b1, NN, 256, 512);
  gemm_bf16<1><<<dim3(MB, 2), 256, 0, stream>>>(ff1o, ffw2t, ff2o, nullptr, NN, 512, 256);
  ln2_k<<<NN / 4, 256, 0, stream>>>(ff2o, ff_b2, x1f, ln_g, ln_b, x2);
  readout_k<<<NG, 256, 0, stream>>>(x2, start, out0);
}

// Round 3
// 1749.821 us; speedup vs baseline: 1.1721x; 1.0654x over previous
//
#include <hip/hip_runtime.h>

#define NN 50000
#define NE 800000
#define NG 128
#define DIN 1280
#define HIDDEN 256
#define BNS 0.9999950000374997f
#define ATT_SCALE 0.027950849718747373f
#define LN_EPS 1e-5f

typedef __attribute__((ext_vector_type(8))) short short8;
typedef __attribute__((ext_vector_type(4))) float floatx4;

__device__ __forceinline__ float b2f(unsigned short u) {
  return __uint_as_float(((unsigned int)u) << 16);
}
__device__ __forceinline__ unsigned short f2b(float f) {
  unsigned int x = __float_as_uint(f);
  x += 0x7fffu + ((x >> 16) & 1u);
  return (unsigned short)(x >> 16);
}

// ---------------- weight prep ----------------
__global__ void transpose_w_k(const float* __restrict__ src, unsigned short* __restrict__ dst,
                              int K, int Nc) {
  int idx = blockIdx.x * 256 + threadIdx.x;
  if (idx >= K * Nc) return;
  int n = idx / K, k = idx % K;
  dst[idx] = f2b(src[(size_t)k * Nc + n]);
}

// M_h = qw_h @ kw_h^T; dst rows [0,1024)
__global__ void mw_k(const float* __restrict__ qw, const float* __restrict__ kw,
                     unsigned short* __restrict__ dst) {
  int col = blockIdx.x;      // 0..1023
  int d = threadIdx.x;       // 0..255
  int hh = col >> 8, dp = col & 255;
  const float* qr = qw + ((size_t)hh * 256 + d) * 256;
  const float* kr = kw + ((size_t)hh * 256 + dp) * 256;
  float s = 0.f;
  for (int e = 0; e < 256; e += 4) {
    float4 a = *(const float4*)(qr + e);
    float4 b = *(const float4*)(kr + e);
    s += a.x * b.x + a.y * b.y + a.z * b.z + a.w * b.w;
  }
  dst[(size_t)col * 256 + d] = f2b(s);
}

// vw [4][256][256] -> dst rows [1024,2048)
__global__ void v_transpose_k(const float* __restrict__ vw, unsigned short* __restrict__ dst) {
  int idx = blockIdx.x * 256 + threadIdx.x;
  if (idx >= 1024 * 256) return;
  int r = idx >> 8;
  int d = idx & 255;
  int hh = r >> 8;
  int e2 = r & 255;
  dst[(size_t)(1024 + r) * 256 + d] = f2b(vw[((size_t)hh * 256 + d) * 256 + e2]);
}

// ---------------- fused h->bf16 conversion + per-graph sum ----------------
__global__ void cvt_avg_k(const float* __restrict__ h, const int* __restrict__ gid,
                          unsigned short* __restrict__ h_bf, float* __restrict__ out1) {
  int row0 = blockIdx.x * 50;
  int tid = threadIdx.x;
  float acc[5] = {0, 0, 0, 0, 0};
  int cur_g = gid[row0];
  for (int r = 0; r < 50; ++r) {
    int row = row0 + r;
    int g = gid[row];
    if (g != cur_g) {
#pragma unroll
      for (int j = 0; j < 5; ++j) {
        atomicAdd(&out1[(size_t)cur_g * DIN + j * 256 + tid], acc[j]);
        acc[j] = 0.f;
      }
      cur_g = g;
    }
#pragma unroll
    for (int j = 0; j < 5; ++j) {
      float v = h[(size_t)row * DIN + j * 256 + tid];
      acc[j] += v;
      h_bf[(size_t)row * DIN + j * 256 + tid] = f2b(v);
    }
  }
#pragma unroll
  for (int j = 0; j < 5; ++j)
    atomicAdd(&out1[(size_t)cur_g * DIN + j * 256 + tid], acc[j]);
}

__global__ void div_avg_k(const int* __restrict__ start, float* __restrict__ out1) {
  int idx = blockIdx.x * 256 + threadIdx.x;
  if (idx >= NG * DIN) return;
  int g = idx / DIN;
  float cnt = (float)(start[g + 1] - start[g]);
  if (cnt < 1.f) cnt = 1.f;
  out1[idx] /= cnt;
}

// ---------------- graph structure ----------------
__global__ void graph_bounds_k(const int* __restrict__ gid, int* __restrict__ start, int n) {
  int i = blockIdx.x * 256 + threadIdx.x;
  if (i >= n) return;
  int g = gid[i];
  if (i == 0) {
    for (int gg = 0; gg <= g; ++gg) start[gg] = 0;
  } else {
    int gp = gid[i - 1];
    for (int gg = gp + 1; gg <= g; ++gg) start[gg] = i;
  }
  if (i == n - 1) {
    for (int gg = g + 1; gg <= NG; ++gg) start[gg] = n;
  }
}

__global__ void degrees_k(const int* __restrict__ src, const int* __restrict__ dst,
                          int* __restrict__ deg_out, int* __restrict__ deg_in, int e) {
  int i = blockIdx.x * 256 + threadIdx.x;
  if (i >= e) return;
  atomicAdd(&deg_out[src[i]], 1);
  atomicAdd(&deg_in[dst[i]], 1);
}

__global__ void invsqrt_k(const int* __restrict__ deg_out, const int* __restrict__ deg_in,
                          float* __restrict__ ns, float* __restrict__ nd, int n) {
  int i = blockIdx.x * 256 + threadIdx.x;
  if (i >= n) return;
  int a = deg_out[i]; if (a < 1) a = 1;
  int b = deg_in[i];  if (b < 1) b = 1;
  ns[i] = rsqrtf((float)a);
  nd[i] = rsqrtf((float)b);
}

// 3-kernel scan: local scans, block-sum scan, add offsets
__global__ void scan_local_k(const int* __restrict__ deg, int* __restrict__ row_ptr,
                             int* __restrict__ bsum) {
  __shared__ int buf[256];
  int b = blockIdx.x, t = threadIdx.x;
  int i = b * 256 + t;
  int v = (i < NN) ? deg[i] : 0;
  buf[t] = v;
  __syncthreads();
  for (int off = 1; off < 256; off <<= 1) {
    int tv = (t >= off) ? buf[t - off] : 0;
    __syncthreads();
    buf[t] += tv;
    __syncthreads();
  }
  if (i < NN) row_ptr[i] = buf[t] - v;
  if (t == 255) bsum[b] = buf[255];
}

__global__ void scan_bsum_k(int* __restrict__ bsum, int* __restrict__ boff, int nb,
                            int* __restrict__ row_ptr) {
  __shared__ int buf[256];
  int t = threadIdx.x;
  int v = (t < nb) ? bsum[t] : 0;
  buf[t] = v;
  __syncthreads();
  for (int off = 1; off < 256; off <<= 1) {
    int tv = (t >= off) ? buf[t - off] : 0;
    __syncthreads();
    buf[t] += tv;
    __syncthreads();
  }
  if (t < nb) boff[t] = buf[t] - v;
  if (t == 0) row_ptr[NN] = NE;
}

__global__ void scan_add_k(int* __restrict__ row_ptr, const int* __restrict__ boff) {
  int i = blockIdx.x * 256 + threadIdx.x;
  if (i >= NN) return;
  row_ptr[i] += boff[blockIdx.x];
}

__global__ void fill_csr_k(const int* __restrict__ src, const int* __restrict__ dst,
                           const int* __restrict__ row_ptr, int* __restrict__ fill,
                           int* __restrict__ csr_src, int e) {
  int i = blockIdx.x * 256 + threadIdx.x;
  if (i >= e) return;
  int d = dst[i];
  int pos = row_ptr[d] + atomicAdd(&fill[d], 1);
  csr_src[pos] = src[i];
}

// ---------------- bf16 MFMA GEMM ----------------
// C[M,Nc] = A[M,K] * Bt[Nc,K]   (both bf16)
// MODE 0: bf16 out; 1: fp32 out; 2: +bias relu bf16 out;
// MODE 4: cols<1024 -> att epilogue (no store), cols>=1024 -> bf16 store ld=1024
// MODE 5: A scaled by ascale[row*4 + (k0>>8)] at staging; bf16 out
template <int MODE>
__global__ __launch_bounds__(256, 2) void gemm_bf16(const unsigned short* __restrict__ A,
                                                    const unsigned short* __restrict__ Bt,
                                                    void* __restrict__ Cout,
                                                    const float* __restrict__ bias,
                                                    int M, int K, int Nc,
                                                    const unsigned short* __restrict__ xtile,
                                                    float* __restrict__ attp,
                                                    const float* __restrict__ ascale) {
  __shared__ unsigned short sbuf[16384];
  unsigned short* lA = sbuf;
  unsigned short* lB = sbuf + 8192;
  const int tid = threadIdx.x;
  const int n0 = blockIdx.x * 128;   // N-dim fastest for A-tile L2 reuse
  const int m0 = blockIdx.y * 128;
  const int w = tid >> 6;
  const int lane = tid & 63;
  const int wr = (w >> 1) * 64;
  const int wc = (w & 1) * 64;
  const int quad = lane >> 4;
  const int l15 = lane & 15;
  const int js = tid & 7;
  const int mbase = tid >> 3;

  floatx4 acc[4][4];
#pragma unroll
  for (int i = 0; i < 4; ++i)
#pragma unroll
    for (int j = 0; j < 4; ++j) acc[i][j] = (floatx4)0.0f;

  for (int k0 = 0; k0 < K; k0 += 64) {
    __syncthreads();
#pragma unroll
    for (int it = 0; it < 4; ++it) {
      int m = it * 32 + mbase;
      int gm = m0 + m;
      if (gm >= M) gm = M - 1;
      uint4 va = *(const uint4*)(A + (size_t)gm * K + k0 + js * 8);
      if (MODE == 5) {
        float s = ascale[(size_t)gm * 4 + (k0 >> 8)];
        unsigned short* pp = (unsigned short*)&va;
#pragma unroll
        for (int c = 0; c < 8; ++c) pp[c] = f2b(b2f(pp[c]) * s);
      }
      int ci_ = js * 128 + (m ^ js);
      *(uint4*)(lA + ci_ * 8) = va;
      int gn = n0 + m;
      uint4 vb = *(const uint4*)(Bt + (size_t)gn * K + k0 + js * 8);
      *(uint4*)(lB + ci_ * 8) = vb;
    }
    __syncthreads();
#pragma unroll
    for (int ks = 0; ks < 2; ++ks) {
      int kb = ks * 4 + quad;
      short8 af[4], bfr[4];
#pragma unroll
      for (int ri = 0; ri < 4; ++ri) {
        int r = wr + ri * 16 + l15;
        af[ri] = *(const short8*)(lA + (kb * 128 + (r ^ kb)) * 8);
      }
#pragma unroll
      for (int ci = 0; ci < 4; ++ci) {
        int c = wc + ci * 16 + l15;
        bfr[ci] = *(const short8*)(lB + (kb * 128 + (c ^ kb)) * 8);
      }
#pragma unroll
      for (int ri = 0; ri < 4; ++ri)
#pragma unroll
        for (int ci = 0; ci < 4; ++ci)
          acc[ri][ci] = __builtin_amdgcn_mfma_f32_16x16x32_bf16(af[ri], bfr[ci], acc[ri][ci], 0, 0, 0);
    }
  }

  if (MODE == 4 && n0 < 1024) {
    // att epilogue: att[n,h] += sum_col acc * xb[n,col]; no C store
    __syncthreads();
    int cb = n0 & 255;
#pragma unroll
    for (int it2 = 0; it2 < 8; ++it2) {
      int linear = it2 * 256 + tid;
      int rr = linear >> 4;
      int c8 = (linear & 15) * 8;
      int gr = m0 + rr;
      if (gr >= M) gr = M - 1;
      *(uint4*)(sbuf + rr * 128 + c8) = *(const uint4*)(xtile + (size_t)gr * 256 + cb + c8);
    }
    __syncthreads();
    int head = n0 >> 8;
#pragma unroll
    for (int ri = 0; ri < 4; ++ri) {
      int lrow = wr + ri * 16 + quad * 4;
#pragma unroll
      for (int r = 0; r < 4; ++r) {
        float p = 0.f;
#pragma unroll
        for (int ci = 0; ci < 4; ++ci)
          p += acc[ri][ci][r] * b2f(sbuf[(lrow + r) * 128 + wc + ci * 16 + l15]);
        p += __shfl_xor(p, 1);
        p += __shfl_xor(p, 2);
        p += __shfl_xor(p, 4);
        p += __shfl_xor(p, 8);
        if (l15 == 0) {
          int grow = m0 + lrow + r;
          if (grow < M) atomicAdd(&attp[(size_t)grow * 4 + head], p * ATT_SCALE);
        }
      }
    }
    return;
  }

#pragma unroll
  for (int ri = 0; ri < 4; ++ri) {
    int row = m0 + wr + ri * 16 + quad * 4;
#pragma unroll
    for (int ci = 0; ci < 4; ++ci) {
      int col = n0 + wc + ci * 16 + l15;
      float bv = (MODE == 2) ? bias[col] : 0.f;
#pragma unroll
      for (int r = 0; r < 4; ++r) {
        if (row + r < M) {
          float v = acc[ri][ci][r];
          if (MODE == 2) { v += bv; v = fmaxf(v, 0.f); }
          if (MODE == 1)
            ((float*)Cout)[(size_t)(row + r) * Nc + col] = v;
          else if (MODE == 4)
            ((unsigned short*)Cout)[(size_t)(row + r) * 1024 + col - 1024] = f2b(v);
          else
            ((unsigned short*)Cout)[(size_t)(row + r) * Nc + col] = f2b(v);
        }
      }
    }
  }
}

// ---------------- GCN aggregation ----------------
__global__ void gcn_agg_k(const unsigned short* __restrict__ m, int ldm,
                          const int* __restrict__ row_ptr, const int* __restrict__ csr_src,
                          const float* __restrict__ ns, const float* __restrict__ nd,
                          const float* __restrict__ bias,
                          const float* __restrict__ bng, const float* __restrict__ bnb,
                          const unsigned short* __restrict__ resid, int ldr,
                          unsigned short* __restrict__ out, int ldo) {
  int node = blockIdx.x * 4 + (threadIdx.x >> 6);
  if (node >= NN) return;
  int lane = threadIdx.x & 63;
  int s = row_ptr[node], e = row_ptr[node + 1];
  float a0 = 0, a1 = 0, a2 = 0, a3 = 0;
  for (int i = s; i < e; ++i) {
    int u = csr_src[i];
    float w = ns[u];
    ushort4 v = *(const ushort4*)(m + (size_t)u * ldm + lane * 4);
    a0 += w * b2f(v.x); a1 += w * b2f(v.y); a2 += w * b2f(v.z); a3 += w * b2f(v.w);
  }
  float ndv = nd[node];
  int col = lane * 4;
  float vals[4] = {a0, a1, a2, a3};
  ushort4 o;
#pragma unroll
  for (int c = 0; c < 4; ++c) {
    float v = vals[c] * ndv + bias[col + c];
    v = bng[col + c] * v * BNS + bnb[col + c];
    v = fmaxf(v, 0.f);
    if (resid) v += b2f(resid[(size_t)node * ldr + col + c]);
    ((unsigned short*)&o)[c] = f2b(v);
  }
  *(ushort4*)(out + (size_t)node * ldo + col) = o;
}

// ---------------- GAT el/er ----------------
__global__ void elr_k(const unsigned short* __restrict__ f, int ldf,
                      const float* __restrict__ al, const float* __restrict__ ar,
                      float* __restrict__ elr) {
  int node = blockIdx.x * 4 + (threadIdx.x >> 6);
  if (node >= NN) return;
  int lane = threadIdx.x & 63;
  int head = lane >> 4;
  int col = lane * 4;
  int dcol = col & 63;
  ushort4 v = *(const ushort4*)(f + (size_t)node * ldf + col);
  float pl = 0, pr = 0;
#pragma unroll
  for (int c = 0; c < 4; ++c) {
    float x = b2f(((unsigned short*)&v)[c]);
    pl += x * al[head * 64 + dcol + c];
    pr += x * ar[head * 64 + dcol + c];
  }
#pragma unroll
  for (int off = 1; off < 16; off <<= 1) {
    pl += __shfl_xor(pl, off);
    pr += __shfl_xor(pr, off);
  }
  if ((lane & 15) == 0) {
    elr[(size_t)node * 8 + head] = pl;
    elr[(size_t)node * 8 + 4 + head] = pr;
  }
}

// ---------------- GAT aggregation ----------------
__global__ void gat_agg_k(const unsigned short* __restrict__ f, int ldf,
                          const int* __restrict__ row_ptr, const int* __restrict__ csr_src,
                          const float* __restrict__ elr,
                          const float* __restrict__ bias,
                          const float* __restrict__ bng, const float* __restrict__ bnb,
                          const unsigned short* __restrict__ resid, int ldr,
                          unsigned short* __restrict__ out, int ldo) {
  int node = blockIdx.x * 4 + (threadIdx.x >> 6);
  if (node >= NN) return;
  int lane = threadIdx.x & 63;
  int s = row_ptr[node], e = row_ptr[node + 1];
  float4 er = *(const float4*)(elr + (size_t)node * 8 + 4);
  float m0 = -1e30f, m1 = -1e30f, m2 = -1e30f, m3 = -1e30f;
  for (int i = s + lane; i < e; i += 64) {
    int u = csr_src[i];
    float4 el = *(const float4*)(elr + (size_t)u * 8);
    float t;
    t = el.x + er.x; t = t > 0.f ? t : 0.2f * t; m0 = fmaxf(m0, t);
    t = el.y + er.y; t = t > 0.f ? t : 0.2f * t; m1 = fmaxf(m1, t);
    t = el.z + er.z; t = t > 0.f ? t : 0.2f * t; m2 = fmaxf(m2, t);
    t = el.w + er.w; t = t > 0.f ? t : 0.2f * t; m3 = fmaxf(m3, t);
  }
#pragma unroll
  for (int off = 1; off < 64; off <<= 1) {
    m0 = fmaxf(m0, __shfl_xor(m0, off));
    m1 = fmaxf(m1, __shfl_xor(m1, off));
    m2 = fmaxf(m2, __shfl_xor(m2, off));
    m3 = fmaxf(m3, __shfl_xor(m3, off));
  }
  float s0 = 0, s1 = 0, s2 = 0, s3 = 0;
  for (int i = s + lane; i < e; i += 64) {
    int u = csr_src[i];
    float4 el = *(const float4*)(elr + (size_t)u * 8);
    float t;
    t = el.x + er.x; t = t > 0.f ? t : 0.2f * t; s0 += expf(t - m0);
    t = el.y + er.y; t = t > 0.f ? t : 0.2f * t; s1 += expf(t - m1);
    t = el.z + er.z; t = t > 0.f ? t : 0.2f * t; s2 += expf(t - m2);
    t = el.w + er.w; t = t > 0.f ? t : 0.2f * t; s3 += expf(t - m3);
  }
#pragma unroll
  for (int off = 1; off < 64; off <<= 1) {
    s0 += __shfl_xor(s0, off);
    s1 += __shfl_xor(s1, off);
    s2 += __shfl_xor(s2, off);
    s3 += __shfl_xor(s3, off);
  }
  int head = lane >> 4;
  float erh = head == 0 ? er.x : head == 1 ? er.y : head == 2 ? er.z : er.w;
  float mh = head == 0 ? m0 : head == 1 ? m1 : head == 2 ? m2 : m3;
  float sh = head == 0 ? s0 : head == 1 ? s1 : head == 2 ? s2 : s3;
  float inv_sh = (sh > 0.f) ? 1.f / sh : 0.f;
  float a0 = 0, a1 = 0, a2 = 0, a3 = 0;
  for (int i = s; i < e; ++i) {
    int u = csr_src[i];
    float t = elr[(size_t)u * 8 + head] + erh;
    t = t > 0.f ? t : 0.2f * t;
    float wgt = expf(t - mh) * inv_sh;
    ushort4 v = *(const ushort4*)(f + (size_t)u * ldf + lane * 4);
    a0 += wgt * b2f(v.x); a1 += wgt * b2f(v.y); a2 += wgt * b2f(v.z); a3 += wgt * b2f(v.w);
  }
  int col = lane * 4;
  float vals[4] = {a0, a1, a2, a3};
  ushort4 o;
#pragma unroll
  for (int c = 0; c < 4; ++c) {
    float v = vals[c] + bias[col + c];
    v = bng[col + c] * v * BNS + bnb[col + c];
    v = (v > 0.f) ? v : (expf(v) - 1.f);
    if (resid) v += b2f(resid[(size_t)node * ldr + col + c]);
    ((unsigned short*)&o)[c] = f2b(v);
  }
  *(ushort4*)(out + (size_t)node * ldo + col) = o;
}

// ---------------- gate combine (glogit bf16 -> xb bf16) ----------------
__global__ void combine_k(const unsigned short* __restrict__ glogit, const float* __restrict__ gate_b,
                          const unsigned short* __restrict__ xcat,
                          unsigned short* __restrict__ xb) {
  int idx = blockIdx.x * 256 + threadIdx.x;
  if (idx >= NN * 64) return;
  int node = idx >> 6;
  int c = (idx & 63) * 4;
  ushort4 gl = *(const ushort4*)(glogit + (size_t)node * HIDDEN + c);
  ushort4 hgv = *(const ushort4*)(xcat + (size_t)node * 512 + c);
  ushort4 hav = *(const ushort4*)(xcat + (size_t)node * 512 + 256 + c);
  ushort4 ob;
  float g;
  g = 1.f / (1.f + expf(-(b2f(gl.x) + gate_b[c + 0]))); ob.x = f2b(g * b2f(hgv.x) + (1.f - g) * b2f(hav.x));
  g = 1.f / (1.f + expf(-(b2f(gl.y) + gate_b[c + 1]))); ob.y = f2b(g * b2f(hgv.y) + (1.f - g) * b2f(hav.y));
  g = 1.f / (1.f + expf(-(b2f(gl.z) + gate_b[c + 2]))); ob.z = f2b(g * b2f(hgv.z) + (1.f - g) * b2f(hav.z));
  g = 1.f / (1.f + expf(-(b2f(gl.w) + gate_b[c + 3]))); ob.w = f2b(g * b2f(hgv.w) + (1.f - g) * b2f(hav.w));
  *(ushort4*)(xb + (size_t)node * HIDDEN + c) = ob;
}

// ---------------- per-graph node softmax ----------------
__global__ void gsoftmax_k(const float* __restrict__ att, const int* __restrict__ start,
                           float* __restrict__ alpha) {
  int g = blockIdx.x;
  int s = start[g], e = start[g + 1];
  int tid = threadIdx.x;
  __shared__ float red[256];
  __shared__ float mh[4], sh[4];
  float lm[4] = {-1e30f, -1e30f, -1e30f, -1e30f};
  for (int i = s + tid; i < e; i += 256) {
    float4 a = *(const float4*)(att + (size_t)i * 4);
    lm[0] = fmaxf(lm[0], a.x); lm[1] = fmaxf(lm[1], a.y);
    lm[2] = fmaxf(lm[2], a.z); lm[3] = fmaxf(lm[3], a.w);
  }
#pragma unroll
  for (int h = 0; h < 4; ++h) {
    red[tid] = lm[h]; __syncthreads();
    for (int off = 128; off > 0; off >>= 1) {
      if (tid < off) red[tid] = fmaxf(red[tid], red[tid + off]);
      __syncthreads();
    }
    if (tid == 0) mh[h] = red[0];
    __syncthreads();
  }
  float ls[4] = {0, 0, 0, 0};
  for (int i = s + tid; i < e; i += 256) {
    float4 a = *(const float4*)(att + (size_t)i * 4);
    ls[0] += expf(a.x - mh[0]); ls[1] += expf(a.y - mh[1]);
    ls[2] += expf(a.z - mh[2]); ls[3] += expf(a.w - mh[3]);
  }
#pragma unroll
  for (int h = 0; h < 4; ++h) {
    red[tid] = ls[h]; __syncthreads();
    for (int off = 128; off > 0; off >>= 1) {
      if (tid < off) red[tid] += red[tid + off];
      __syncthreads();
    }
    if (tid == 0) sh[h] = red[0];
    __syncthreads();
  }
  for (int i = s + tid; i < e; i += 256) {
    float4 a = *(const float4*)(att + (size_t)i * 4);
    float4 o;
    o.x = expf(a.x - mh[0]) / sh[0];
    o.y = expf(a.y - mh[1]) / sh[1];
    o.z = expf(a.z - mh[2]) / sh[2];
    o.w = expf(a.w - mh[3]) / sh[3];
    *(float4*)(alpha + (size_t)i * 4) = o;
  }
}

// ---------------- LayerNorms (all bf16 in/out) ----------------
__global__ void ln1_k(const unsigned short* __restrict__ mo, const unsigned short* __restrict__ x,
                      const float* __restrict__ g, const float* __restrict__ b,
                      unsigned short* __restrict__ x1) {
  int node = blockIdx.x * 4 + (threadIdx.x >> 6);
  if (node >= NN) return;
  int lane = threadIdx.x & 63;
  int c = lane * 4;
  ushort4 a = *(const ushort4*)(mo + (size_t)node * HIDDEN + c);
  ushort4 xx = *(const ushort4*)(x + (size_t)node * HIDDEN + c);
  float v0 = b2f(a.x) + b2f(xx.x), v1 = b2f(a.y) + b2f(xx.y);
  float v2 = b2f(a.z) + b2f(xx.z), v3 = b2f(a.w) + b2f(xx.w);
  float sm = v0 + v1 + v2 + v3;
#pragma unroll
  for (int off = 1; off < 64; off <<= 1) sm += __shfl_xor(sm, off);
  float mu = sm * (1.f / 256.f);
  float d0 = v0 - mu, d1 = v1 - mu, d2 = v2 - mu, d3 = v3 - mu;
  float sq = d0 * d0 + d1 * d1 + d2 * d2 + d3 * d3;
#pragma unroll
  for (int off = 1; off < 64; off <<= 1) sq += __shfl_xor(sq, off);
  float inv = rsqrtf(sq * (1.f / 256.f) + LN_EPS);
  ushort4 ob;
  ob.x = f2b(g[c + 0] * d0 * inv + b[c + 0]);
  ob.y = f2b(g[c + 1] * d1 * inv + b[c + 1]);
  ob.z = f2b(g[c + 2] * d2 * inv + b[c + 2]);
  ob.w = f2b(g[c + 3] * d3 * inv + b[c + 3]);
  *(ushort4*)(x1 + (size_t)node * HIDDEN + c) = ob;
}

__global__ void ln2_k(const unsigned short* __restrict__ ff2o, const float* __restrict__ ffb2,
                      const unsigned short* __restrict__ x1,
                      const float* __restrict__ g, const float* __restrict__ b,
                      unsigned short* __restrict__ x2) {
  int node = blockIdx.x * 4 + (threadIdx.x >> 6);
  if (node >= NN) return;
  int lane = threadIdx.x & 63;
  int c = lane * 4;
  ushort4 a = *(const ushort4*)(ff2o + (size_t)node * HIDDEN + c);
  ushort4 xx = *(const ushort4*)(x1 + (size_t)node * HIDDEN + c);
  float v0 = b2f(a.x) + ffb2[c + 0] + b2f(xx.x), v1 = b2f(a.y) + ffb2[c + 1] + b2f(xx.y);
  float v2 = b2f(a.z) + ffb2[c + 2] + b2f(xx.z), v3 = b2f(a.w) + ffb2[c + 3] + b2f(xx.w);
  float sm = v0 + v1 + v2 + v3;
#pragma unroll
  for (int off = 1; off < 64; off <<= 1) sm += __shfl_xor(sm, off);
  float mu = sm * (1.f / 256.f);
  float d0 = v0 - mu, d1 = v1 - mu, d2 = v2 - mu, d3 = v3 - mu;
  float sq = d0 * d0 + d1 * d1 + d2 * d2 + d3 * d3;
#pragma unroll
  for (int off = 1; off < 64; off <<= 1) sq += __shfl_xor(sq, off);
  float inv = rsqrtf(sq * (1.f / 256.f) + LN_EPS);
  ushort4 ob;
  ob.x = f2b(g[c + 0] * d0 * inv + b[c + 0]);
  ob.y = f2b(g[c + 1] * d1 * inv + b[c + 1]);
  ob.z = f2b(g[c + 2] * d2 * inv + b[c + 2]);
  ob.w = f2b(g[c + 3] * d3 * inv + b[c + 3]);
  *(ushort4*)(x2 + (size_t)node * HIDDEN + c) = ob;
}

// ---------------- readout (output 0) ----------------
__global__ void readout_k(const unsigned short* __restrict__ x2, const int* __restrict__ start,
                          float* __restrict__ out0) {
  int g = blockIdx.x;
  int c = threadIdx.x;
  float acc = 0.f;
  for (int i = start[g]; i < start[g + 1]; ++i) acc += b2f(x2[(size_t)i * HIDDEN + c]);
  out0[(size_t)g * HIDDEN + c] = acc;
}

// ---------------- workspace layout (bytes) ----------------
// region [0,128e6): phase1 h_bf / phase2 yv(102.4e6) / phase3 ff1o@0, ff2o@51.2e6, x2@76.8e6
static const size_t OFF_BUFA   = 0;
static const size_t OFF_C01    = 128000000;
static const size_t OFF_HG0    = 179200000;
static const size_t OFF_HA0    = 204800000;
static const size_t OFF_M1     = 230400000;
static const size_t OFF_F1     = 256000000;
static const size_t OFF_XCAT   = 281600000;
static const size_t OFF_GLOGIT = 332800000;
static const size_t OFF_XB     = 358400000;
static const size_t OFF_MO     = 384000000;
static const size_t OFF_X1     = 409600000;
static const size_t OFF_ATT    = 435200000;
static const size_t OFF_ALPHA  = OFF_ATT + 800000;
static const size_t OFF_ELR0   = OFF_ALPHA + 800000;
static const size_t OFF_ELR1   = OFF_ELR0 + 1600000;
static const size_t OFF_START  = OFF_ELR1 + 1600000;
static const size_t OFF_DEGO   = OFF_START + 1024;
static const size_t OFF_DEGI   = OFF_DEGO + 200704;
static const size_t OFF_NS     = OFF_DEGI + 200704;
static const size_t OFF_ND     = OFF_NS + 200704;
static const size_t OFF_ROWP   = OFF_ND + 200704;
static const size_t OFF_FILL   = OFF_ROWP + 200704;
static const size_t OFF_BSUM   = OFF_FILL + 200704;
static const size_t OFF_BOFF   = OFF_BSUM + 1024;
static const size_t OFF_CSRS   = OFF_BOFF + 1024;
static const size_t OFF_W01T   = OFF_CSRS + 3200000;
static const size_t OFF_W1T    = OFF_W01T + 1310720;
static const size_t OFF_W1GT   = OFF_W1T + 131072;
static const size_t OFF_GATEWT = OFF_W1GT + 131072;
static const size_t OFF_WMVT   = OFF_GATEWT + 262144;
static const size_t OFF_CTWT   = OFF_WMVT + 1048576;
static const size_t OFF_FFW1T  = OFF_CTWT + 524288;
static const size_t OFF_FFW2T  = OFF_FFW1T + 262144;
static const size_t WS_NEED    = OFF_FFW2T + 262144;

extern "C" void kernel_launch(void* const* d_in, const int* in_sizes, int n_in,
                              void* d_out, int out_size, void* d_ws, size_t ws_size,
                              hipStream_t stream) {
  if (ws_size < WS_NEED) return;

  const float* h       = (const float*)d_in[0];
  const float* gcn_w0  = (const float*)d_in[1];
  const float* gcn_b0  = (const float*)d_in[2];
  const float* gcn_w1  = (const float*)d_in[3];
  const float* gcn_b1  = (const float*)d_in[4];
  const float* bn_gcn0_g = (const float*)d_in[5];
  const float* bn_gcn0_b = (const float*)d_in[6];
  const float* bn_gcn1_g = (const float*)d_in[7];
  const float* bn_gcn1_b = (const float*)d_in[8];
  const float* gat_w0  = (const float*)d_in[9];
  const float* gat_al0 = (const float*)d_in[10];
  const float* gat_ar0 = (const float*)d_in[11];
  const float* gat_bias0 = (const float*)d_in[12];
  const float* gat_w1  = (const float*)d_in[13];
  const float* gat_al1 = (const float*)d_in[14];
  const float* gat_ar1 = (const float*)d_in[15];
  const float* gat_bias1 = (const float*)d_in[16];
  const float* bn_gat0_g = (const float*)d_in[17];
  const float* bn_gat0_b = (const float*)d_in[18];
  const float* bn_gat1_g = (const float*)d_in[19];
  const float* bn_gat1_b = (const float*)d_in[20];
  const float* gate_w  = (const float*)d_in[21];
  const float* gate_b  = (const float*)d_in[22];
  const float* qw      = (const float*)d_in[23];
  const float* kw      = (const float*)d_in[24];
  const float* vw      = (const float*)d_in[25];
  const float* ct_w    = (const float*)d_in[26];
  const float* ff_w1   = (const float*)d_in[27];
  const float* ff_b1   = (const float*)d_in[28];
  const float* ff_w2   = (const float*)d_in[29];
  const float* ff_b2   = (const float*)d_in[30];
  const float* ln_g    = (const float*)d_in[31];
  const float* ln_b    = (const float*)d_in[32];
  const int* srcv = (const int*)d_in[33];
  const int* dstv = (const int*)d_in[34];
  const int* gid  = (const int*)d_in[35];

  char* ws = (char*)d_ws;
  unsigned short* h_bf = (unsigned short*)(ws + OFF_BUFA);
  unsigned short* yv   = (unsigned short*)(ws + OFF_BUFA);           // [N][1024] V only
  unsigned short* ff1o = (unsigned short*)(ws + OFF_BUFA);
  unsigned short* ff2o = (unsigned short*)(ws + OFF_BUFA + 51200000);
  unsigned short* x2   = (unsigned short*)(ws + OFF_BUFA + 76800000);
  unsigned short* c01  = (unsigned short*)(ws + OFF_C01);
  unsigned short* hg0  = (unsigned short*)(ws + OFF_HG0);
  unsigned short* ha0  = (unsigned short*)(ws + OFF_HA0);
  unsigned short* m1   = (unsigned short*)(ws + OFF_M1);
  unsigned short* f1   = (unsigned short*)(ws + OFF_F1);
  unsigned short* xcat = (unsigned short*)(ws + OFF_XCAT);
  unsigned short* glogit = (unsigned short*)(ws + OFF_GLOGIT);
  unsigned short* xb   = (unsigned short*)(ws + OFF_XB);
  unsigned short* mo   = (unsigned short*)(ws + OFF_MO);
  unsigned short* x1   = (unsigned short*)(ws + OFF_X1);
  float* att           = (float*)(ws + OFF_ATT);
  float* alpha         = (float*)(ws + OFF_ALPHA);
  float* elr0          = (float*)(ws + OFF_ELR0);
  float* elr1          = (float*)(ws + OFF_ELR1);
  int* start   = (int*)(ws + OFF_START);
  int* deg_out = (int*)(ws + OFF_DEGO);
  int* deg_in  = (int*)(ws + OFF_DEGI);
  float* ns    = (float*)(ws + OFF_NS);
  float* nd    = (float*)(ws + OFF_ND);
  int* row_ptr = (int*)(ws + OFF_ROWP);
  int* fill    = (int*)(ws + OFF_FILL);
  int* bsum    = (int*)(ws + OFF_BSUM);
  int* boff    = (int*)(ws + OFF_BOFF);
  int* csr_src = (int*)(ws + OFF_CSRS);
  unsigned short* w01t   = (unsigned short*)(ws + OFF_W01T);
  unsigned short* w1t    = (unsigned short*)(ws + OFF_W1T);
  unsigned short* w1gt   = (unsigned short*)(ws + OFF_W1GT);
  unsigned short* gatewt = (unsigned short*)(ws + OFF_GATEWT);
  unsigned short* wmvt   = (unsigned short*)(ws + OFF_WMVT);
  unsigned short* ctwt   = (unsigned short*)(ws + OFF_CTWT);
  unsigned short* ffw1t  = (unsigned short*)(ws + OFF_FFW1T);
  unsigned short* ffw2t  = (unsigned short*)(ws + OFF_FFW2T);

  float* out0 = (float*)d_out;            // readout [128,256]
  float* out1 = out0 + NG * HIDDEN;       // init_avg_h [128,1280]

  hipMemsetAsync(deg_out, 0, NN * 4, stream);
  hipMemsetAsync(deg_in, 0, NN * 4, stream);
  hipMemsetAsync(fill, 0, NN * 4, stream);
  hipMemsetAsync(out1, 0, NG * DIN * 4, stream);
  hipMemsetAsync(att, 0, NN * 4 * 4, stream);

  // weight prep
  transpose_w_k<<<(1280 * 256 + 255) / 256, 256, 0, stream>>>(gcn_w0, w01t, 1280, 256);
  transpose_w_k<<<(1280 * 256 + 255) / 256, 256, 0, stream>>>(gat_w0, w01t + 256 * 1280, 1280, 256);
  transpose_w_k<<<(256 * 256 + 255) / 256, 256, 0, stream>>>(gcn_w1, w1t, 256, 256);
  transpose_w_k<<<(256 * 256 + 255) / 256, 256, 0, stream>>>(gat_w1, w1gt, 256, 256);
  transpose_w_k<<<(512 * 256 + 255) / 256, 256, 0, stream>>>(gate_w, gatewt, 512, 256);
  mw_k<<<1024, 256, 0, stream>>>(qw, kw, wmvt);
  v_transpose_k<<<1024, 256, 0, stream>>>(vw, wmvt);
  transpose_w_k<<<(1024 * 256 + 255) / 256, 256, 0, stream>>>(ct_w, ctwt, 1024, 256);
  transpose_w_k<<<(256 * 512 + 255) / 256, 256, 0, stream>>>(ff_w1, ffw1t, 256, 512);
  transpose_w_k<<<(512 * 256 + 255) / 256, 256, 0, stream>>>(ff_w2, ffw2t, 512, 256);

  // graph structure
  graph_bounds_k<<<(NN + 255) / 256, 256, 0, stream>>>(gid, start, NN);
  degrees_k<<<(NE + 255) / 256, 256, 0, stream>>>(srcv, dstv, deg_out, deg_in, NE);
  invsqrt_k<<<(NN + 255) / 256, 256, 0, stream>>>(deg_out, deg_in, ns, nd, NN);
  const int NB_SCAN = (NN + 255) / 256;
  scan_local_k<<<NB_SCAN, 256, 0, stream>>>(deg_in, row_ptr, bsum);
  scan_bsum_k<<<1, 256, 0, stream>>>(bsum, boff, NB_SCAN, row_ptr);
  scan_add_k<<<NB_SCAN, 256, 0, stream>>>(row_ptr, boff);
  fill_csr_k<<<(NE + 255) / 256, 256, 0, stream>>>(srcv, dstv, row_ptr, fill, csr_src, NE);

  // fused h->bf16 + per-graph sums, then divide
  cvt_avg_k<<<NN / 50, 256, 0, stream>>>(h, gid, h_bf, out1);
  div_avg_k<<<(NG * DIN + 255) / 256, 256, 0, stream>>>(start, out1);

  const int MB = (NN + 127) / 128;
  // GEMM1: h @ [gcn_w0 | gat_w0] -> c01 [N,512]
  gemm_bf16<0><<<dim3(4, MB), 256, 0, stream>>>(h_bf, w01t, c01, nullptr, NN, 1280, 512,
                                                nullptr, nullptr, nullptr);
  gcn_agg_k<<<NN / 4, 256, 0, stream>>>(c01, 512, row_ptr, csr_src, ns, nd,
                                        gcn_b0, bn_gcn0_g, bn_gcn0_b, nullptr, 0, hg0, 256);
  elr_k<<<NN / 4, 256, 0, stream>>>(c01 + 256, 512, gat_al0, gat_ar0, elr0);
  gat_agg_k<<<NN / 4, 256, 0, stream>>>(c01 + 256, 512, row_ptr, csr_src, elr0,
                                        gat_bias0, bn_gat0_g, bn_gat0_b, nullptr, 0, ha0, 256);
  // layer 1
  gemm_bf16<0><<<dim3(2, MB), 256, 0, stream>>>(hg0, w1t, m1, nullptr, NN, 256, 256,
                                                nullptr, nullptr, nullptr);
  gcn_agg_k<<<NN / 4, 256, 0, stream>>>(m1, 256, row_ptr, csr_src, ns, nd,
                                        gcn_b1, bn_gcn1_g, bn_gcn1_b, hg0, 256, xcat, 512);
  gemm_bf16<0><<<dim3(2, MB), 256, 0, stream>>>(ha0, w1gt, f1, nullptr, NN, 256, 256,
                                                nullptr, nullptr, nullptr);
  elr_k<<<NN / 4, 256, 0, stream>>>(f1, 256, gat_al1, gat_ar1, elr1);
  gat_agg_k<<<NN / 4, 256, 0, stream>>>(f1, 256, row_ptr, csr_src, elr1,
                                        gat_bias1, bn_gat1_g, bn_gat1_b, ha0, 256, xcat + 256, 512);
  // gate
  gemm_bf16<0><<<dim3(2, MB), 256, 0, stream>>>(xcat, gatewt, glogit, nullptr, NN, 512, 256,
                                                nullptr, nullptr, nullptr);
  combine_k<<<NN / 4, 256, 0, stream>>>(glogit, gate_b, xcat, xb);
  // transformer: att fused into M-part epilogue; V-part stored to yv
  gemm_bf16<4><<<dim3(16, MB), 256, 0, stream>>>(xb, wmvt, yv, nullptr, NN, 256, 2048,
                                                 xb, att, nullptr);
  gsoftmax_k<<<NG, 256, 0, stream>>>(att, start, alpha);
  gemm_bf16<5><<<dim3(2, MB), 256, 0, stream>>>(yv, ctwt, mo, nullptr, NN, 1024, 256,
                                                nullptr, nullptr, alpha);
  ln1_k<<<NN / 4, 256, 0, stream>>>(mo, xb, ln_g, ln_b, x1);
  gemm_bf16<2><<<dim3(4, MB), 256, 0, stream>>>(x1, ffw1t, ff1o, ff_b1, NN, 256, 512,
                                                nullptr, nullptr, nullptr);
  gemm_bf16<0><<<dim3(2, MB), 256, 0, stream>>>(ff1o, ffw2t, ff2o, nullptr, NN, 512, 256,
                                                nullptr, nullptr, nullptr);
  ln2_k<<<NN / 4, 256, 0, stream>>>(ff2o, ff_b2, x1, ln_g, ln_b, x2);
  readout_k<<<NG, 256, 0, stream>>>(x2, start, out0);
}